// Round 1
// baseline (1064.897 us; speedup 1.0000x reference)
//
#include <hip/hip_runtime.h>
#include <cstdint>
#include <cstddef>

// GNNDi: B=2, V=256, H=128, L=3, GroupNorm32 head.
// Layout: e, e_new stored [b][i][j][h] (h contiguous), fp32.

#define EPSV 1e-5f

__device__ __forceinline__ float sigmoidf_(float x) { return 1.f / (1.f + __expf(-x)); }

// ---------------- K0: fold edge-embed Linears: W_comb(6,H) = W_eattr @ W_ee, b_comb = b_eattr@W_ee + b_ee
__global__ void k_wcomb(const float* __restrict__ W_ea, const float* __restrict__ b_ea,
                        const float* __restrict__ W_ee, const float* __restrict__ b_ee,
                        float* __restrict__ Wcb, float* __restrict__ bcb)
{
    int t = threadIdx.x; // 128 threads, t = output channel
    float wc0=0,wc1=0,wc2=0,wc3=0,wc4=0,wc5=0,bv=0;
    for (int m = 0; m < 128; ++m) {
        float we = W_ee[m*128 + t];
        wc0 = fmaf(W_ea[0*128+m], we, wc0);
        wc1 = fmaf(W_ea[1*128+m], we, wc1);
        wc2 = fmaf(W_ea[2*128+m], we, wc2);
        wc3 = fmaf(W_ea[3*128+m], we, wc3);
        wc4 = fmaf(W_ea[4*128+m], we, wc4);
        wc5 = fmaf(b_ea[m] * 0.f + W_ea[5*128+m], we, wc5); // keep simple
        bv  = fmaf(b_ea[m], we, bv);
    }
    Wcb[0*128+t]=wc0; Wcb[1*128+t]=wc1; Wcb[2*128+t]=wc2;
    Wcb[3*128+t]=wc3; Wcb[4*128+t]=wc4; Wcb[5*128+t]=wc5;
    bcb[t] = bv + b_ee[t];
}

// ---------------- K1: node embedding: h[b,v,:] = emb_type[x[b,v]] @ W_node + b_node
__global__ void k_node(const int* __restrict__ x, const float* __restrict__ emb,
                       const float* __restrict__ W_node, const float* __restrict__ b_node,
                       float* __restrict__ h)
{
    __shared__ float se[128];
    int blk = blockIdx.x, t = threadIdx.x;
    int xv = x[blk];
    se[t] = emb[xv*128 + t];
    __syncthreads();
    float acc = b_node[t];
    for (int k = 0; k < 128; ++k) acc = fmaf(se[k], W_node[k*128+t], acc);
    h[blk*128+t] = acc;
}

// ---------------- K2: e0[b,i,j,:] = sum_c adj[b,c,i,j]*W_comb[c,:] + b_comb
__global__ void k_einit(const float* __restrict__ adj, const float* __restrict__ Wcb,
                        const float* __restrict__ bcb, float* __restrict__ e)
{
    __shared__ float sW[6*128];
    __shared__ float sb[128];
    int blk = blockIdx.x, t = threadIdx.x;
    int b = blk >> 8, i = blk & 255;
    for (int idx = t; idx < 768; idx += 128) sW[idx] = Wcb[idx];
    sb[t] = bcb[t];
    __syncthreads();
    const float* arow = adj + (size_t)b*393216 + (size_t)i*256;
    float* erow = e + (size_t)blk*32768;
    for (int j = 0; j < 256; ++j) {
        float a0 = arow[j];
        float a1 = arow[65536 + j];
        float a2 = arow[131072 + j];
        float a3 = arow[196608 + j];
        float a4 = arow[262144 + j];
        float a5 = arow[327680 + j];
        float v = sb[t];
        v = fmaf(a0, sW[t],     v);
        v = fmaf(a1, sW[128+t], v);
        v = fmaf(a2, sW[256+t], v);
        v = fmaf(a3, sW[384+t], v);
        v = fmaf(a4, sW[512+t], v);
        v = fmaf(a5, sW[640+t], v);
        erow[j*128 + t] = v;
    }
}

// ---------------- K3: Uh/Vh/Ah/Bh = h @ W* + b*   (B*V rows)
__global__ void k_hgemm(const float* __restrict__ h,
    const float* __restrict__ Wu_l, const float* __restrict__ bu_l,
    const float* __restrict__ Wv_l, const float* __restrict__ bv_l,
    const float* __restrict__ Wa_l, const float* __restrict__ ba_l,
    const float* __restrict__ Wb_l, const float* __restrict__ bb_l,
    float* __restrict__ Uh, float* __restrict__ Vh, float* __restrict__ Ah, float* __restrict__ Bh)
{
    __shared__ float sh[128];
    int blk = blockIdx.x, t = threadIdx.x;
    sh[t] = h[blk*128+t];
    __syncthreads();
    float au=bu_l[t], av=bv_l[t], aa=ba_l[t], ab=bb_l[t];
    for (int k = 0; k < 128; ++k) {
        float hv = sh[k];
        au = fmaf(hv, Wu_l[k*128+t], au);
        av = fmaf(hv, Wv_l[k*128+t], av);
        aa = fmaf(hv, Wa_l[k*128+t], aa);
        ab = fmaf(hv, Wb_l[k*128+t], ab);
    }
    Uh[blk*128+t]=au; Vh[blk*128+t]=av; Ah[blk*128+t]=aa; Bh[blk*128+t]=ab;
}

// ---------------- K4: e_new = e@Wc + bc + Ah[j] + Bh[i]; gates=sigmoid(e_new)*mask;
//                      agg = sum_j gates*Vh[j]; h += relu(LN(Uh+agg))
__global__ __launch_bounds__(256) void k_enew_agg(
    const float* __restrict__ e, float* __restrict__ enew,
    const float* __restrict__ Wc_l, const float* __restrict__ bc_l,
    const float* __restrict__ Ah, const float* __restrict__ Bh,
    const float* __restrict__ Uh, const float* __restrict__ Vh,
    const float* __restrict__ adj, float* __restrict__ h,
    const float* __restrict__ g_l, const float* __restrict__ bta_l)
{
    __shared__ __align__(16) float sW[128*128];   // 64 KB: Wc
    __shared__ __align__(16) float se[64*128];    // 32 KB: e tile
    __shared__ __align__(16) float sagg[8][128];  // 4 KB
    __shared__ float sred[4];
    const int t = threadIdx.x;
    const int blk = blockIdx.x;
    const int b = blk >> 8, i = blk & 255;
    const int cg = t & 31, rg = t >> 5;
    const int c4 = cg << 2;
    for (int idx = t*4; idx < 128*128; idx += 1024)
        *(float4*)&sW[idx] = *(const float4*)&Wc_l[idx];
    const float4 bcv = *(const float4*)&bc_l[c4];
    const float4 Bhv = *(const float4*)&Bh[blk*128 + c4];
    const float* maskrow = adj + (size_t)b*393216 + (size_t)i*256;
    const size_t rowbase = (size_t)blk*32768;
    float ag0=0, ag1=0, ag2=0, ag3=0;
    for (int chunk = 0; chunk < 4; ++chunk) {
        const int j0 = chunk << 6;
        __syncthreads();
        for (int idx = t*4; idx < 64*128; idx += 1024)
            *(float4*)&se[idx] = *(const float4*)&e[rowbase + (size_t)j0*128 + idx];
        __syncthreads();
        float4 acc[8];
        #pragma unroll
        for (int jj = 0; jj < 8; ++jj) {
            const int j = j0 + (rg<<3) + jj;
            const float4 av = *(const float4*)&Ah[(b*256 + j)*128 + c4];
            acc[jj].x = bcv.x + Bhv.x + av.x;
            acc[jj].y = bcv.y + Bhv.y + av.y;
            acc[jj].z = bcv.z + Bhv.z + av.z;
            acc[jj].w = bcv.w + Bhv.w + av.w;
        }
        for (int k = 0; k < 128; k += 4) {
            const float4 w0 = *(const float4*)&sW[(k+0)*128 + c4];
            const float4 w1 = *(const float4*)&sW[(k+1)*128 + c4];
            const float4 w2 = *(const float4*)&sW[(k+2)*128 + c4];
            const float4 w3 = *(const float4*)&sW[(k+3)*128 + c4];
            #pragma unroll
            for (int jj = 0; jj < 8; ++jj) {
                const float4 ev = *(const float4*)&se[((rg<<3)+jj)*128 + k];
                acc[jj].x = fmaf(ev.x,w0.x,acc[jj].x); acc[jj].x = fmaf(ev.y,w1.x,acc[jj].x);
                acc[jj].x = fmaf(ev.z,w2.x,acc[jj].x); acc[jj].x = fmaf(ev.w,w3.x,acc[jj].x);
                acc[jj].y = fmaf(ev.x,w0.y,acc[jj].y); acc[jj].y = fmaf(ev.y,w1.y,acc[jj].y);
                acc[jj].y = fmaf(ev.z,w2.y,acc[jj].y); acc[jj].y = fmaf(ev.w,w3.y,acc[jj].y);
                acc[jj].z = fmaf(ev.x,w0.z,acc[jj].z); acc[jj].z = fmaf(ev.y,w1.z,acc[jj].z);
                acc[jj].z = fmaf(ev.z,w2.z,acc[jj].z); acc[jj].z = fmaf(ev.w,w3.z,acc[jj].z);
                acc[jj].w = fmaf(ev.x,w0.w,acc[jj].w); acc[jj].w = fmaf(ev.y,w1.w,acc[jj].w);
                acc[jj].w = fmaf(ev.z,w2.w,acc[jj].w); acc[jj].w = fmaf(ev.w,w3.w,acc[jj].w);
            }
        }
        #pragma unroll
        for (int jj = 0; jj < 8; ++jj) {
            const int j = j0 + (rg<<3) + jj;
            *(float4*)&enew[rowbase + (size_t)j*128 + c4] = acc[jj];
            const float m = maskrow[j];
            const float4 vh = *(const float4*)&Vh[(b*256 + j)*128 + c4];
            ag0 = fmaf(m*sigmoidf_(acc[jj].x), vh.x, ag0);
            ag1 = fmaf(m*sigmoidf_(acc[jj].y), vh.y, ag1);
            ag2 = fmaf(m*sigmoidf_(acc[jj].z), vh.z, ag2);
            ag3 = fmaf(m*sigmoidf_(acc[jj].w), vh.w, ag3);
        }
    }
    __syncthreads();
    sagg[rg][c4+0]=ag0; sagg[rg][c4+1]=ag1; sagg[rg][c4+2]=ag2; sagg[rg][c4+3]=ag3;
    __syncthreads();
    float s=0,q=0,val=0;
    if (t < 128) {
        float a = 0;
        #pragma unroll
        for (int r = 0; r < 8; ++r) a += sagg[r][t];
        val = Uh[blk*128+t] + a;
        s = val; q = val*val;
        #pragma unroll
        for (int off = 32; off; off >>= 1) { s += __shfl_down(s,off); q += __shfl_down(q,off); }
        if ((t&63)==0){ sred[t>>6]=s; sred[2+(t>>6)]=q; }
    }
    __syncthreads();
    if (t < 128) {
        s = sred[0]+sred[1]; q = sred[2]+sred[3];
        float mean = s*(1.f/128.f);
        float var  = q*(1.f/128.f) - mean*mean;
        float nv = (val-mean)*rsqrtf(var+EPSV)*g_l[t] + bta_l[t];
        h[blk*128+t] += fmaxf(nv, 0.f);
    }
}

// ---------------- K5: e = e_in + silu(LN_plo(relu(LN_lne(e_new)))) @ plo_W + plo_bW
__global__ __launch_bounds__(256) void k_eupd(
    float* __restrict__ e, const float* __restrict__ enew,
    const float* __restrict__ lg, const float* __restrict__ lb,
    const float* __restrict__ pg, const float* __restrict__ pb,
    const float* __restrict__ PW, const float* __restrict__ pbW)
{
    __shared__ __align__(16) float sW[128*128];  // 64 KB: plo_W
    __shared__ __align__(16) float su[64*128];   // 32 KB: silu(LN(...)) tile
    const int t = threadIdx.x;
    const int blk = blockIdx.x;
    const int cg = t & 31, rg = t >> 5, c4 = cg << 2;
    const int wave = t >> 6, lane = t & 63;
    for (int idx = t*4; idx < 128*128; idx += 1024)
        *(float4*)&sW[idx] = *(const float4*)&PW[idx];
    const size_t rowbase = (size_t)blk*32768;
    const float lg0 = lg[lane], lg1 = lg[lane+64];
    const float lb0 = lb[lane], lb1 = lb[lane+64];
    const float pg0 = pg[lane], pg1 = pg[lane+64];
    const float pb0 = pb[lane], pb1 = pb[lane+64];
    const float4 pbw = *(const float4*)&pbW[c4];
    for (int chunk = 0; chunk < 4; ++chunk) {
        const int j0 = chunk << 6;
        __syncthreads();
        // phase A: per-wave row processing (LN -> relu -> LN -> silu), 16 rows/wave
        for (int r = wave; r < 64; r += 4) {
            const int j = j0 + r;
            const float x0 = enew[rowbase + (size_t)j*128 + lane];
            const float x1 = enew[rowbase + (size_t)j*128 + lane + 64];
            float s = x0 + x1, q = x0*x0 + x1*x1;
            #pragma unroll
            for (int off = 32; off; off >>= 1) { s += __shfl_xor(s,off); q += __shfl_xor(q,off); }
            float mean = s*(1.f/128.f);
            float rs = rsqrtf(q*(1.f/128.f) - mean*mean + EPSV);
            float t0 = fmaxf((x0-mean)*rs*lg0 + lb0, 0.f);
            float t1 = fmaxf((x1-mean)*rs*lg1 + lb1, 0.f);
            s = t0 + t1; q = t0*t0 + t1*t1;
            #pragma unroll
            for (int off = 32; off; off >>= 1) { s += __shfl_xor(s,off); q += __shfl_xor(q,off); }
            mean = s*(1.f/128.f);
            rs = rsqrtf(q*(1.f/128.f) - mean*mean + EPSV);
            float u0 = (t0-mean)*rs*pg0 + pb0;
            float u1 = (t1-mean)*rs*pg1 + pb1;
            u0 = u0 * sigmoidf_(u0);
            u1 = u1 * sigmoidf_(u1);
            su[r*128 + lane] = u0;
            su[r*128 + lane + 64] = u1;
        }
        __syncthreads();
        // phase B: u @ plo_W, add residual + bias, store e in place
        float4 acc[8];
        #pragma unroll
        for (int jj = 0; jj < 8; ++jj) {
            const int j = j0 + (rg<<3) + jj;
            const float4 ein = *(const float4*)&e[rowbase + (size_t)j*128 + c4];
            acc[jj].x = ein.x + pbw.x;
            acc[jj].y = ein.y + pbw.y;
            acc[jj].z = ein.z + pbw.z;
            acc[jj].w = ein.w + pbw.w;
        }
        for (int k = 0; k < 128; k += 4) {
            const float4 w0 = *(const float4*)&sW[(k+0)*128 + c4];
            const float4 w1 = *(const float4*)&sW[(k+1)*128 + c4];
            const float4 w2 = *(const float4*)&sW[(k+2)*128 + c4];
            const float4 w3 = *(const float4*)&sW[(k+3)*128 + c4];
            #pragma unroll
            for (int jj = 0; jj < 8; ++jj) {
                const float4 ev = *(const float4*)&su[((rg<<3)+jj)*128 + k];
                acc[jj].x = fmaf(ev.x,w0.x,acc[jj].x); acc[jj].x = fmaf(ev.y,w1.x,acc[jj].x);
                acc[jj].x = fmaf(ev.z,w2.x,acc[jj].x); acc[jj].x = fmaf(ev.w,w3.x,acc[jj].x);
                acc[jj].y = fmaf(ev.x,w0.y,acc[jj].y); acc[jj].y = fmaf(ev.y,w1.y,acc[jj].y);
                acc[jj].y = fmaf(ev.z,w2.y,acc[jj].y); acc[jj].y = fmaf(ev.w,w3.y,acc[jj].y);
                acc[jj].z = fmaf(ev.x,w0.z,acc[jj].z); acc[jj].z = fmaf(ev.y,w1.z,acc[jj].z);
                acc[jj].z = fmaf(ev.z,w2.z,acc[jj].z); acc[jj].z = fmaf(ev.w,w3.z,acc[jj].z);
                acc[jj].w = fmaf(ev.x,w0.w,acc[jj].w); acc[jj].w = fmaf(ev.y,w1.w,acc[jj].w);
                acc[jj].w = fmaf(ev.z,w2.w,acc[jj].w); acc[jj].w = fmaf(ev.w,w3.w,acc[jj].w);
            }
        }
        #pragma unroll
        for (int jj = 0; jj < 8; ++jj) {
            const int j = j0 + (rg<<3) + jj;
            *(float4*)&e[rowbase + (size_t)j*128 + c4] = acc[jj];
        }
    }
}

// ---------------- K6: per-channel sums for GroupNorm
__global__ void k_gstats(const float* __restrict__ e, float* __restrict__ gsum, float* __restrict__ gsq)
{
    int blk = blockIdx.x, t = threadIdx.x;
    int b = blk >> 8;
    const float* erow = e + (size_t)blk*32768;
    float s=0,q=0;
    for (int j = 0; j < 256; ++j) { float v = erow[j*128+t]; s += v; q = fmaf(v,v,q); }
    atomicAdd(&gsum[b*128+t], s);
    atomicAdd(&gsq[b*128+t], q);
}

// ---------------- K7: finalize group stats (B*32 groups, 4 channels each)
__global__ void k_gfin(const float* __restrict__ gsum, const float* __restrict__ gsq,
                       float* __restrict__ gmu, float* __restrict__ grs)
{
    int t = threadIdx.x; // 64
    int b = t >> 5, g = t & 31;
    int base = b*128 + g*4;
    float s = gsum[base]+gsum[base+1]+gsum[base+2]+gsum[base+3];
    float q = gsq[base]+gsq[base+1]+gsq[base+2]+gsq[base+3];
    const float invN = 1.f/(4.f*65536.f);
    float mu = s*invN;
    float var = q*invN - mu*mu;
    gmu[t] = mu;
    grs[t] = rsqrtf(var + EPSV);
}

// ---------------- K8: out[b,0,i,j] = sum_c relu(z*gn_g+gn_b)*W_out[c] + b_out
__global__ void k_head(const float* __restrict__ e, const float* __restrict__ gmu,
                       const float* __restrict__ grs, const float* __restrict__ gn_g,
                       const float* __restrict__ gn_b, const float* __restrict__ W_out,
                       const float* __restrict__ b_out, float* __restrict__ out)
{
    __shared__ float sred[2];
    int blk = blockIdx.x, t = threadIdx.x;
    int b = blk >> 8;
    int g = t >> 2;
    float mu = gmu[b*32+g], rs = grs[b*32+g];
    float gg = gn_g[t]*rs;
    float gb = gn_b[t] - mu*gg;
    float wo = W_out[t];
    float bo = b_out[0];
    const float* erow = e + (size_t)blk*32768;
    float* orow = out + (size_t)blk*256;
    int wave = t >> 6, lane = t & 63;
    for (int j = 0; j < 256; ++j) {
        float v = erow[j*128 + t];
        float r = fmaxf(fmaf(v, gg, gb), 0.f) * wo;
        #pragma unroll
        for (int off = 32; off; off >>= 1) r += __shfl_down(r, off);
        if (lane == 0) sred[wave] = r;
        __syncthreads();
        if (t == 0) orow[j] = sred[0] + sred[1] + bo;
        __syncthreads();
    }
}

extern "C" void kernel_launch(void* const* d_in, const int* in_sizes, int n_in,
                              void* d_out, int out_size, void* d_ws, size_t ws_size,
                              hipStream_t stream)
{
    const int*   x      = (const int*)  d_in[0];
    const float* adj    = (const float*)d_in[1];
    const float* emb    = (const float*)d_in[2];
    const float* W_node = (const float*)d_in[3];
    const float* b_node = (const float*)d_in[4];
    const float* W_ea   = (const float*)d_in[5];
    const float* b_ea   = (const float*)d_in[6];
    const float* W_ee   = (const float*)d_in[7];
    const float* b_ee   = (const float*)d_in[8];
    const float* Wu     = (const float*)d_in[9];
    const float* bu     = (const float*)d_in[10];
    const float* Wv     = (const float*)d_in[11];
    const float* bv     = (const float*)d_in[12];
    const float* Wa     = (const float*)d_in[13];
    const float* ba     = (const float*)d_in[14];
    const float* Wb     = (const float*)d_in[15];
    const float* bb     = (const float*)d_in[16];
    const float* Wc     = (const float*)d_in[17];
    const float* bc     = (const float*)d_in[18];
    const float* lnh_g  = (const float*)d_in[19];
    const float* lnh_b  = (const float*)d_in[20];
    const float* lne_g  = (const float*)d_in[21];
    const float* lne_b  = (const float*)d_in[22];
    const float* plo_g  = (const float*)d_in[23];
    const float* plo_b  = (const float*)d_in[24];
    const float* plo_W  = (const float*)d_in[25];
    const float* plo_bW = (const float*)d_in[26];
    const float* gn_g   = (const float*)d_in[27];
    const float* gn_b   = (const float*)d_in[28];
    const float* W_out  = (const float*)d_in[29];
    const float* b_out  = (const float*)d_in[30];
    float* out = (float*)d_out;

    float* ws = (float*)d_ws;
    size_t off = 0;
    float* e    = ws + off; off += (size_t)2*256*256*128;  // 16,777,216
    float* enew = ws + off; off += (size_t)2*256*256*128;  // 16,777,216
    float* h    = ws + off; off += 65536;
    float* Uh   = ws + off; off += 65536;
    float* Vh   = ws + off; off += 65536;
    float* Ah   = ws + off; off += 65536;
    float* Bh   = ws + off; off += 65536;
    float* Wcb  = ws + off; off += 768;
    float* bcb  = ws + off; off += 128;
    float* gsum = ws + off; off += 256;
    float* gsq  = ws + off; off += 256;
    float* gmu  = ws + off; off += 64;
    float* grs  = ws + off; off += 64;
    // required ws: ~135.5 MB (assumed available)

    k_wcomb<<<1, 128, 0, stream>>>(W_ea, b_ea, W_ee, b_ee, Wcb, bcb);
    k_node<<<512, 128, 0, stream>>>(x, emb, W_node, b_node, h);
    k_einit<<<512, 128, 0, stream>>>(adj, Wcb, bcb, e);

    for (int l = 0; l < 3; ++l) {
        const float* Wu_l = Wu + (size_t)l*16384;
        const float* Wv_l = Wv + (size_t)l*16384;
        const float* Wa_l = Wa + (size_t)l*16384;
        const float* Wb_l = Wb + (size_t)l*16384;
        const float* Wc_l = Wc + (size_t)l*16384;
        const float* PW_l = plo_W + (size_t)l*16384;
        k_hgemm<<<512, 128, 0, stream>>>(h, Wu_l, bu + l*128, Wv_l, bv + l*128,
                                         Wa_l, ba + l*128, Wb_l, bb + l*128,
                                         Uh, Vh, Ah, Bh);
        k_enew_agg<<<512, 256, 0, stream>>>(e, enew, Wc_l, bc + l*128,
                                            Ah, Bh, Uh, Vh, adj, h,
                                            lnh_g + l*128, lnh_b + l*128);
        k_eupd<<<512, 256, 0, stream>>>(e, enew,
                                        lne_g + l*128, lne_b + l*128,
                                        plo_g + l*128, plo_b + l*128,
                                        PW_l, plo_bW + l*128);
    }

    hipMemsetAsync(gsum, 0, 512*sizeof(float), stream); // gsum+gsq contiguous
    k_gstats<<<512, 128, 0, stream>>>(e, gsum, gsq);
    k_gfin<<<1, 64, 0, stream>>>(gsum, gsq, gmu, grs);
    k_head<<<512, 128, 0, stream>>>(e, gmu, grs, gn_g, gn_b, W_out, b_out, out);
}

// Round 2
// 529.984 us; speedup vs baseline: 2.0093x; 2.0093x over previous
//
#include <hip/hip_runtime.h>
#include <cstdint>
#include <cstddef>

// GNNDi: B=2, V=256, H=128, L=3, GroupNorm32 head. e stored [b][i][j][h] fp32.

#define EPSV 1e-5f

typedef __attribute__((ext_vector_type(8))) short short8v;  // 8 bf16 (4 VGPR)
typedef __attribute__((ext_vector_type(4))) float f32x4;

__device__ __forceinline__ float sigmoidf_(float x) { return 1.f / (1.f + __expf(-x)); }

__device__ __forceinline__ unsigned short f2bf(float x) {
    unsigned int u = __float_as_uint(x);
    unsigned int r = u + 0x7FFFu + ((u >> 16) & 1u);   // RNE
    return (unsigned short)(r >> 16);
}
__device__ __forceinline__ short8v pack8(float4 a, float4 b) {
    short8v r;
    r[0]=(short)f2bf(a.x); r[1]=(short)f2bf(a.y); r[2]=(short)f2bf(a.z); r[3]=(short)f2bf(a.w);
    r[4]=(short)f2bf(b.x); r[5]=(short)f2bf(b.y); r[6]=(short)f2bf(b.z); r[7]=(short)f2bf(b.w);
    return r;
}
#define SWZ(row, cb) ((cb) ^ (((row) & 7) << 4))

// ---------------- K0: fold edge-embed Linears
__global__ void k_wcomb(const float* __restrict__ W_ea, const float* __restrict__ b_ea,
                        const float* __restrict__ W_ee, const float* __restrict__ b_ee,
                        float* __restrict__ Wcb, float* __restrict__ bcb)
{
    int t = threadIdx.x; // 128
    float wc0=0,wc1=0,wc2=0,wc3=0,wc4=0,wc5=0,bv=0;
    for (int m = 0; m < 128; ++m) {
        float we = W_ee[m*128 + t];
        wc0 = fmaf(W_ea[0*128+m], we, wc0);
        wc1 = fmaf(W_ea[1*128+m], we, wc1);
        wc2 = fmaf(W_ea[2*128+m], we, wc2);
        wc3 = fmaf(W_ea[3*128+m], we, wc3);
        wc4 = fmaf(W_ea[4*128+m], we, wc4);
        wc5 = fmaf(W_ea[5*128+m], we, wc5);
        bv  = fmaf(b_ea[m], we, bv);
    }
    Wcb[0*128+t]=wc0; Wcb[1*128+t]=wc1; Wcb[2*128+t]=wc2;
    Wcb[3*128+t]=wc3; Wcb[4*128+t]=wc4; Wcb[5*128+t]=wc5;
    bcb[t] = bv + b_ee[t];
}

// ---------------- K1: node embedding
__global__ void k_node(const int* __restrict__ x, const float* __restrict__ emb,
                       const float* __restrict__ W_node, const float* __restrict__ b_node,
                       float* __restrict__ h)
{
    __shared__ float se[128];
    int blk = blockIdx.x, t = threadIdx.x;
    int xv = x[blk];
    se[t] = emb[xv*128 + t];
    __syncthreads();
    float acc = b_node[t];
    for (int k = 0; k < 128; ++k) acc = fmaf(se[k], W_node[k*128+t], acc);
    h[blk*128+t] = acc;
}

// ---------------- K2: e0 init
__global__ void k_einit(const float* __restrict__ adj, const float* __restrict__ Wcb,
                        const float* __restrict__ bcb, float* __restrict__ e)
{
    __shared__ float sW[6*128];
    __shared__ float sb[128];
    int blk = blockIdx.x, t = threadIdx.x;
    int b = blk >> 8, i = blk & 255;
    for (int idx = t; idx < 768; idx += 128) sW[idx] = Wcb[idx];
    sb[t] = bcb[t];
    __syncthreads();
    const float* arow = adj + (size_t)b*393216 + (size_t)i*256;
    float* erow = e + (size_t)blk*32768;
    for (int j = 0; j < 256; ++j) {
        float a0 = arow[j];
        float a1 = arow[65536 + j];
        float a2 = arow[131072 + j];
        float a3 = arow[196608 + j];
        float a4 = arow[262144 + j];
        float a5 = arow[327680 + j];
        float v = sb[t];
        v = fmaf(a0, sW[t],     v);
        v = fmaf(a1, sW[128+t], v);
        v = fmaf(a2, sW[256+t], v);
        v = fmaf(a3, sW[384+t], v);
        v = fmaf(a4, sW[512+t], v);
        v = fmaf(a5, sW[640+t], v);
        erow[j*128 + t] = v;
    }
}

// ---------------- K3: Uh/Bh normal; Vh/Ah transposed [b][n][v]
__global__ void k_hgemm(const float* __restrict__ h,
    const float* __restrict__ Wu_l, const float* __restrict__ bu_l,
    const float* __restrict__ Wv_l, const float* __restrict__ bv_l,
    const float* __restrict__ Wa_l, const float* __restrict__ ba_l,
    const float* __restrict__ Wb_l, const float* __restrict__ bb_l,
    float* __restrict__ Uh, float* __restrict__ VhT, float* __restrict__ AhT,
    float* __restrict__ Bh)
{
    __shared__ float sh[128];
    int blk = blockIdx.x, t = threadIdx.x;
    int b = blk >> 8, v = blk & 255;
    sh[t] = h[blk*128+t];
    __syncthreads();
    float au=bu_l[t], av=bv_l[t], aa=ba_l[t], ab=bb_l[t];
    for (int k = 0; k < 128; ++k) {
        float hv = sh[k];
        au = fmaf(hv, Wu_l[k*128+t], au);
        av = fmaf(hv, Wv_l[k*128+t], av);
        aa = fmaf(hv, Wa_l[k*128+t], aa);
        ab = fmaf(hv, Wb_l[k*128+t], ab);
    }
    Uh[blk*128+t]=au; Bh[blk*128+t]=ab;
    VhT[(size_t)(b*128+t)*256 + v] = av;
    AhT[(size_t)(b*128+t)*256 + v] = aa;
}

// ---------------- K4: fused layer: e_new (MFMA) -> gates/agg -> LN chain -> plo GEMM (MFMA)
//                      -> e out; h update; optional GN channel stats
__global__ __launch_bounds__(256) void k_layer(
    float* __restrict__ e,
    const float* __restrict__ Wc_l, const float* __restrict__ bc_l,
    const float* __restrict__ AhT, const float* __restrict__ Bh,
    const float* __restrict__ Uh, const float* __restrict__ VhT,
    const float* __restrict__ adj, float* __restrict__ h,
    const float* __restrict__ lnh_g, const float* __restrict__ lnh_b,
    const float* __restrict__ lne_g, const float* __restrict__ lne_b,
    const float* __restrict__ plo_g, const float* __restrict__ plo_b,
    const float* __restrict__ PW_l, const float* __restrict__ pbW_l,
    float* __restrict__ gsum, float* __restrict__ gsq, int do_stats)
{
    __shared__ __align__(16) char sBuf[32768];   // weight staging (bf16) then fp32 out tile
    __shared__ __align__(16) char sEa[16384];    // bf16 [64][128] swizzled (Ea then Ua)
    __shared__ float sS[512];                    // [64 rows][4 waves][s,q]
    __shared__ float sMu[64];
    __shared__ float sRs[64];
    __shared__ float sAgg[128];
    __shared__ float sred[4];

    const int t = threadIdx.x;
    const int blk = blockIdx.x;
    const int b = blk >> 8, i = blk & 255;
    const int w = t >> 6, lane = t & 63;
    const int lane16 = lane & 15, g = lane >> 4;
    const int n0 = w << 5;
    const int col0 = n0 + lane16, col1 = n0 + 16 + lane16;
    const size_t rowbase = (size_t)blk * 32768;

    // ---- preload weight B-fragments (bf16) via LDS staging
    short* sW16 = (short*)sBuf;
    short8v wcF[4][2], ploF[4][2];
    for (int pass = 0; pass < 2; ++pass) {
        const float* Wg = pass ? PW_l : Wc_l;
        __syncthreads();
        for (int base = t*8; base < 16384; base += 2048) {
            float4 f0 = *(const float4*)&Wg[base];
            float4 f1 = *(const float4*)&Wg[base+4];
            *(short8v*)&sW16[base] = pack8(f0, f1);
        }
        __syncthreads();
        #pragma unroll
        for (int kst = 0; kst < 4; ++kst) {
            #pragma unroll
            for (int nt = 0; nt < 2; ++nt) {
                const int coln = n0 + nt*16 + lane16;
                short8v v;
                #pragma unroll
                for (int ee = 0; ee < 8; ++ee)
                    v[ee] = sW16[(kst*32 + g*8 + ee)*128 + coln];
                if (pass) ploF[kst][nt] = v; else wcF[kst][nt] = v;
            }
        }
    }

    // ---- per-lane constants
    const float bcB0 = bc_l[col0] + Bh[blk*128 + col0];
    const float bcB1 = bc_l[col1] + Bh[blk*128 + col1];
    const float lg0 = lne_g[col0], lg1 = lne_g[col1];
    const float lb0 = lne_b[col0], lb1 = lne_b[col1];
    const float pg0 = plo_g[col0], pg1 = plo_g[col1];
    const float pb0 = plo_b[col0], pb1 = plo_b[col1];
    const float pw0 = pbW_l[col0], pw1 = pbW_l[col1];
    const float* adjm = adj + (size_t)b*393216 + (size_t)i*256;

    float agg0 = 0.f, agg1 = 0.f;
    float gs0 = 0.f, gq0 = 0.f, gs1 = 0.f, gq1 = 0.f;
    float tv[4][2][4];

    const int rA = t >> 2, cA = t & 3;

    for (int c = 0; c < 4; ++c) {
        const int j0 = c << 6;
        // phase A: stage e chunk -> sEa (bf16, swizzled)
        {
            const float* src = e + rowbase + (size_t)(j0 + rA)*128 + cA*32;
            #pragma unroll
            for (int ii = 0; ii < 4; ++ii) {
                float4 f0 = *(const float4*)&src[ii*8];
                float4 f1 = *(const float4*)&src[ii*8 + 4];
                *(short8v*)(sEa + rA*256 + SWZ(rA, cA*64 + ii*16)) = pack8(f0, f1);
            }
        }
        __syncthreads();
        // phase B: GEMM1 (e@Wc) + biases + gates/agg; keep e_new in tv
        #pragma unroll
        for (int m = 0; m < 4; ++m) {
            const int arow = m*16 + lane16;
            f32x4 ac0 = {0.f,0.f,0.f,0.f}, ac1 = {0.f,0.f,0.f,0.f};
            #pragma unroll
            for (int kst = 0; kst < 4; ++kst) {
                short8v a8 = *(const short8v*)(sEa + arow*256 + SWZ(arow, kst*64 + g*16));
                ac0 = __builtin_amdgcn_mfma_f32_16x16x32_bf16(a8, wcF[kst][0], ac0, 0, 0, 0);
                ac1 = __builtin_amdgcn_mfma_f32_16x16x32_bf16(a8, wcF[kst][1], ac1, 0, 0, 0);
            }
            const int jb = j0 + m*16 + g*4;
            const float4 ah0 = *(const float4*)&AhT[(size_t)(b*128 + col0)*256 + jb];
            const float4 ah1 = *(const float4*)&AhT[(size_t)(b*128 + col1)*256 + jb];
            const float4 vh0 = *(const float4*)&VhT[(size_t)(b*128 + col0)*256 + jb];
            const float4 vh1 = *(const float4*)&VhT[(size_t)(b*128 + col1)*256 + jb];
            const float4 mk  = *(const float4*)&adjm[jb];
            const float* ah0p = (const float*)&ah0; const float* ah1p = (const float*)&ah1;
            const float* vh0p = (const float*)&vh0; const float* vh1p = (const float*)&vh1;
            const float* mkp  = (const float*)&mk;
            #pragma unroll
            for (int r = 0; r < 4; ++r) {
                float t0 = ac0[r] + bcB0 + ah0p[r];
                float t1 = ac1[r] + bcB1 + ah1p[r];
                agg0 = fmaf(mkp[r]*sigmoidf_(t0), vh0p[r], agg0);
                agg1 = fmaf(mkp[r]*sigmoidf_(t1), vh1p[r], agg1);
                tv[m][0][r] = t0; tv[m][1][r] = t1;
            }
        }
        // stats1 (mean/var of e_new per row)
        #pragma unroll
        for (int m = 0; m < 4; ++m) {
            #pragma unroll
            for (int r = 0; r < 4; ++r) {
                float s = tv[m][0][r] + tv[m][1][r];
                float q = tv[m][0][r]*tv[m][0][r] + tv[m][1][r]*tv[m][1][r];
                s += __shfl_xor(s, 1);  q += __shfl_xor(q, 1);
                s += __shfl_xor(s, 2);  q += __shfl_xor(q, 2);
                s += __shfl_xor(s, 4);  q += __shfl_xor(q, 4);
                s += __shfl_xor(s, 8);  q += __shfl_xor(q, 8);
                if (lane16 == 0) {
                    int row = m*16 + g*4 + r;
                    sS[row*8 + w*2] = s; sS[row*8 + w*2 + 1] = q;
                }
            }
        }
        __syncthreads();
        if (t < 64) {
            float s = sS[t*8] + sS[t*8+2] + sS[t*8+4] + sS[t*8+6];
            float q = sS[t*8+1] + sS[t*8+3] + sS[t*8+5] + sS[t*8+7];
            float mu = s * (1.f/128.f);
            sMu[t] = mu; sRs[t] = rsqrtf(q*(1.f/128.f) - mu*mu + EPSV);
        }
        __syncthreads();
        // LN1 + relu (overwrite tv)
        #pragma unroll
        for (int m = 0; m < 4; ++m) {
            #pragma unroll
            for (int r = 0; r < 4; ++r) {
                int row = m*16 + g*4 + r;
                float mu = sMu[row], rs = sRs[row];
                tv[m][0][r] = fmaxf(fmaf((tv[m][0][r]-mu)*rs, lg0, lb0), 0.f);
                tv[m][1][r] = fmaxf(fmaf((tv[m][1][r]-mu)*rs, lg1, lb1), 0.f);
            }
        }
        // stats2 (mean/var of relu'd values per row)
        #pragma unroll
        for (int m = 0; m < 4; ++m) {
            #pragma unroll
            for (int r = 0; r < 4; ++r) {
                float s = tv[m][0][r] + tv[m][1][r];
                float q = tv[m][0][r]*tv[m][0][r] + tv[m][1][r]*tv[m][1][r];
                s += __shfl_xor(s, 1);  q += __shfl_xor(q, 1);
                s += __shfl_xor(s, 2);  q += __shfl_xor(q, 2);
                s += __shfl_xor(s, 4);  q += __shfl_xor(q, 4);
                s += __shfl_xor(s, 8);  q += __shfl_xor(q, 8);
                if (lane16 == 0) {
                    int row = m*16 + g*4 + r;
                    sS[row*8 + w*2] = s; sS[row*8 + w*2 + 1] = q;
                }
            }
        }
        __syncthreads();
        if (t < 64) {
            float s = sS[t*8] + sS[t*8+2] + sS[t*8+4] + sS[t*8+6];
            float q = sS[t*8+1] + sS[t*8+3] + sS[t*8+5] + sS[t*8+7];
            float mu = s * (1.f/128.f);
            sMu[t] = mu; sRs[t] = rsqrtf(q*(1.f/128.f) - mu*mu + EPSV);
        }
        __syncthreads();
        // LN2 + silu -> write Ua (bf16, swizzled; reuses sEa)
        #pragma unroll
        for (int m = 0; m < 4; ++m) {
            #pragma unroll
            for (int r = 0; r < 4; ++r) {
                int row = m*16 + g*4 + r;
                float mu = sMu[row], rs = sRs[row];
                float u0 = fmaf((tv[m][0][r]-mu)*rs, pg0, pb0);
                float u1 = fmaf((tv[m][1][r]-mu)*rs, pg1, pb1);
                u0 = u0 * sigmoidf_(u0);
                u1 = u1 * sigmoidf_(u1);
                *(short*)(sEa + row*256 + SWZ(row, col0*2)) = (short)f2bf(u0);
                *(short*)(sEa + row*256 + SWZ(row, col1*2)) = (short)f2bf(u1);
            }
        }
        __syncthreads();
        // phase C: GEMM2 (u@plo_W) + residual; stage fp32 out tile
        float* sOut = (float*)sBuf;
        #pragma unroll
        for (int m = 0; m < 4; ++m) {
            const int arow = m*16 + lane16;
            f32x4 ac0 = {0.f,0.f,0.f,0.f}, ac1 = {0.f,0.f,0.f,0.f};
            #pragma unroll
            for (int kst = 0; kst < 4; ++kst) {
                short8v a8 = *(const short8v*)(sEa + arow*256 + SWZ(arow, kst*64 + g*16));
                ac0 = __builtin_amdgcn_mfma_f32_16x16x32_bf16(a8, ploF[kst][0], ac0, 0, 0, 0);
                ac1 = __builtin_amdgcn_mfma_f32_16x16x32_bf16(a8, ploF[kst][1], ac1, 0, 0, 0);
            }
            #pragma unroll
            for (int r = 0; r < 4; ++r) {
                int row = m*16 + g*4 + r;
                int j = j0 + row;
                float o0 = ac0[r] + pw0 + e[rowbase + (size_t)j*128 + col0];
                float o1 = ac1[r] + pw1 + e[rowbase + (size_t)j*128 + col1];
                if (do_stats) {
                    gs0 += o0; gq0 = fmaf(o0, o0, gq0);
                    gs1 += o1; gq1 = fmaf(o1, o1, gq1);
                }
                *(float*)((char*)sOut + row*512 + SWZ(row, col0*4)) = o0;
                *(float*)((char*)sOut + row*512 + SWZ(row, col1*4)) = o1;
            }
        }
        __syncthreads();
        // coalesced writeback of e chunk
        {
            float* dst = e + rowbase + (size_t)(j0 + rA)*128 + cA*32;
            #pragma unroll
            for (int ii = 0; ii < 8; ++ii) {
                float4 v = *(const float4*)((char*)sOut + rA*512 + SWZ(rA, cA*128 + ii*16));
                *(float4*)&dst[ii*4] = v;
            }
        }
        __syncthreads();
    }

    // ---- agg finalize across g-groups; h update
    agg0 += __shfl_xor(agg0, 16); agg0 += __shfl_xor(agg0, 32);
    agg1 += __shfl_xor(agg1, 16); agg1 += __shfl_xor(agg1, 32);
    if (lane < 16) { sAgg[col0] = agg0; sAgg[col1] = agg1; }
    __syncthreads();
    float s = 0.f, q = 0.f, val = 0.f;
    if (t < 128) {
        val = Uh[blk*128 + t] + sAgg[t];
        s = val; q = val*val;
        #pragma unroll
        for (int off = 32; off; off >>= 1) { s += __shfl_down(s, off); q += __shfl_down(q, off); }
        if ((t & 63) == 0) { sred[t>>6] = s; sred[2 + (t>>6)] = q; }
    }
    __syncthreads();
    if (t < 128) {
        s = sred[0] + sred[1]; q = sred[2] + sred[3];
        float mean = s * (1.f/128.f);
        float var  = q * (1.f/128.f) - mean*mean;
        float nv = (val - mean) * rsqrtf(var + EPSV) * lnh_g[t] + lnh_b[t];
        h[blk*128 + t] += fmaxf(nv, 0.f);
    }
    // ---- GroupNorm channel partial sums (last layer only)
    if (do_stats) {
        gs0 += __shfl_xor(gs0, 16); gs0 += __shfl_xor(gs0, 32);
        gq0 += __shfl_xor(gq0, 16); gq0 += __shfl_xor(gq0, 32);
        gs1 += __shfl_xor(gs1, 16); gs1 += __shfl_xor(gs1, 32);
        gq1 += __shfl_xor(gq1, 16); gq1 += __shfl_xor(gq1, 32);
        if (lane < 16) {
            atomicAdd(&gsum[b*128 + col0], gs0); atomicAdd(&gsq[b*128 + col0], gq0);
            atomicAdd(&gsum[b*128 + col1], gs1); atomicAdd(&gsq[b*128 + col1], gq1);
        }
    }
}

// ---------------- K7: finalize group stats
__global__ void k_gfin(const float* __restrict__ gsum, const float* __restrict__ gsq,
                       float* __restrict__ gmu, float* __restrict__ grs)
{
    int t = threadIdx.x; // 64
    int b = t >> 5, g = t & 31;
    int base = b*128 + g*4;
    float s = gsum[base]+gsum[base+1]+gsum[base+2]+gsum[base+3];
    float q = gsq[base]+gsq[base+1]+gsq[base+2]+gsq[base+3];
    const float invN = 1.f/(4.f*65536.f);
    float mu = s*invN;
    float var = q*invN - mu*mu;
    gmu[t] = mu;
    grs[t] = rsqrtf(var + EPSV);
}

// ---------------- K8: head: GN transform -> relu -> 1x1 conv (dot over 128 ch)
__global__ void k_head(const float* __restrict__ e, const float* __restrict__ gmu,
                       const float* __restrict__ grs, const float* __restrict__ gn_g,
                       const float* __restrict__ gn_b, const float* __restrict__ W_out,
                       const float* __restrict__ b_out, float* __restrict__ out)
{
    int blk = blockIdx.x, t = threadIdx.x;
    int b = blk >> 8;
    int w = t >> 6, lane = t & 63;
    int c0 = lane, c1 = lane + 64;
    float mu0 = gmu[b*32 + (c0>>2)], rs0 = grs[b*32 + (c0>>2)];
    float mu1 = gmu[b*32 + (c1>>2)], rs1 = grs[b*32 + (c1>>2)];
    float gg0 = gn_g[c0]*rs0, gb0 = gn_b[c0] - mu0*gg0;
    float gg1 = gn_g[c1]*rs1, gb1 = gn_b[c1] - mu1*gg1;
    float wo0 = W_out[c0], wo1 = W_out[c1];
    float bo = b_out[0];
    const float* erow = e + (size_t)blk*32768;
    float* orow = out + (size_t)blk*256;
    for (int jj = 0; jj < 64; ++jj) {
        int j = w*64 + jj;
        float v0 = erow[(size_t)j*128 + c0];
        float v1 = erow[(size_t)j*128 + c1];
        float r = fmaxf(fmaf(v0, gg0, gb0), 0.f)*wo0 + fmaxf(fmaf(v1, gg1, gb1), 0.f)*wo1;
        #pragma unroll
        for (int off = 32; off; off >>= 1) r += __shfl_down(r, off);
        if (lane == 0) orow[j] = r + bo;
    }
}

extern "C" void kernel_launch(void* const* d_in, const int* in_sizes, int n_in,
                              void* d_out, int out_size, void* d_ws, size_t ws_size,
                              hipStream_t stream)
{
    const int*   x      = (const int*)  d_in[0];
    const float* adj    = (const float*)d_in[1];
    const float* emb    = (const float*)d_in[2];
    const float* W_node = (const float*)d_in[3];
    const float* b_node = (const float*)d_in[4];
    const float* W_ea   = (const float*)d_in[5];
    const float* b_ea   = (const float*)d_in[6];
    const float* W_ee   = (const float*)d_in[7];
    const float* b_ee   = (const float*)d_in[8];
    const float* Wu     = (const float*)d_in[9];
    const float* bu     = (const float*)d_in[10];
    const float* Wv     = (const float*)d_in[11];
    const float* bv     = (const float*)d_in[12];
    const float* Wa     = (const float*)d_in[13];
    const float* ba     = (const float*)d_in[14];
    const float* Wb     = (const float*)d_in[15];
    const float* bb     = (const float*)d_in[16];
    const float* Wc     = (const float*)d_in[17];
    const float* bc     = (const float*)d_in[18];
    const float* lnh_g  = (const float*)d_in[19];
    const float* lnh_b  = (const float*)d_in[20];
    const float* lne_g  = (const float*)d_in[21];
    const float* lne_b  = (const float*)d_in[22];
    const float* plo_g  = (const float*)d_in[23];
    const float* plo_b  = (const float*)d_in[24];
    const float* plo_W  = (const float*)d_in[25];
    const float* plo_bW = (const float*)d_in[26];
    const float* gn_g   = (const float*)d_in[27];
    const float* gn_b   = (const float*)d_in[28];
    const float* W_out  = (const float*)d_in[29];
    const float* b_out  = (const float*)d_in[30];
    float* out = (float*)d_out;

    float* ws = (float*)d_ws;
    size_t off = 0;
    float* e    = ws + off; off += (size_t)2*256*256*128;  // 67 MB
    float* h    = ws + off; off += 65536;
    float* Uh   = ws + off; off += 65536;
    float* Bh   = ws + off; off += 65536;
    float* VhT  = ws + off; off += 65536;
    float* AhT  = ws + off; off += 65536;
    float* Wcb  = ws + off; off += 768;
    float* bcb  = ws + off; off += 128;
    float* gsum = ws + off; off += 256;
    float* gsq  = ws + off; off += 256;   // contiguous with gsum
    float* gmu  = ws + off; off += 64;
    float* grs  = ws + off; off += 64;

    k_wcomb<<<1, 128, 0, stream>>>(W_ea, b_ea, W_ee, b_ee, Wcb, bcb);
    k_node<<<512, 128, 0, stream>>>(x, emb, W_node, b_node, h);
    k_einit<<<512, 128, 0, stream>>>(adj, Wcb, bcb, e);
    hipMemsetAsync(gsum, 0, 512*sizeof(float), stream);

    for (int l = 0; l < 3; ++l) {
        k_hgemm<<<512, 128, 0, stream>>>(h,
            Wu + (size_t)l*16384, bu + l*128,
            Wv + (size_t)l*16384, bv + l*128,
            Wa + (size_t)l*16384, ba + l*128,
            Wb + (size_t)l*16384, bb + l*128,
            Uh, VhT, AhT, Bh);
        k_layer<<<512, 256, 0, stream>>>(e,
            Wc + (size_t)l*16384, bc + l*128,
            AhT, Bh, Uh, VhT, adj, h,
            lnh_g + l*128, lnh_b + l*128,
            lne_g + l*128, lne_b + l*128,
            plo_g + l*128, plo_b + l*128,
            plo_W + (size_t)l*16384, plo_bW + l*128,
            gsum, gsq, (l == 2) ? 1 : 0);
    }

    k_gfin<<<1, 64, 0, stream>>>(gsum, gsq, gmu, grs);
    k_head<<<512, 256, 0, stream>>>(e, gmu, grs, gn_g, gn_b, W_out, b_out, out);
}

// Round 3
// 474.912 us; speedup vs baseline: 2.2423x; 1.1160x over previous
//
#include <hip/hip_runtime.h>
#include <cstdint>
#include <cstddef>

// GNNDi: B=2, V=256, H=128, L=3, GroupNorm32 head. e stored [b][i][j][h] fp32.

#define EPSV 1e-5f

typedef __attribute__((ext_vector_type(8))) short short8v;  // 8 bf16
typedef __attribute__((ext_vector_type(4))) float f32x4;

__device__ __forceinline__ float sigmoidf_(float x) { return 1.f / (1.f + __expf(-x)); }

__device__ __forceinline__ unsigned short f2bf(float x) {
    unsigned int u = __float_as_uint(x);
    unsigned int r = u + 0x7FFFu + ((u >> 16) & 1u);   // RNE
    return (unsigned short)(r >> 16);
}
__device__ __forceinline__ short8v pack8(float4 a, float4 b) {
    short8v r;
    r[0]=(short)f2bf(a.x); r[1]=(short)f2bf(a.y); r[2]=(short)f2bf(a.z); r[3]=(short)f2bf(a.w);
    r[4]=(short)f2bf(b.x); r[5]=(short)f2bf(b.y); r[6]=(short)f2bf(b.z); r[7]=(short)f2bf(b.w);
    return r;
}
#define SWZ(row, cb) ((cb) ^ (((row) & 7) << 4))

// ---------------- K_prep: node embed (blocks 0..511), wcomb (block 512), weight transpose (513..518)
__global__ void k_prep(const int* __restrict__ x, const float* __restrict__ emb,
                       const float* __restrict__ W_node, const float* __restrict__ b_node,
                       float* __restrict__ h,
                       const float* __restrict__ W_ea, const float* __restrict__ b_ea,
                       const float* __restrict__ W_ee, const float* __restrict__ b_ee,
                       float* __restrict__ Wcb, float* __restrict__ bcb,
                       const float* __restrict__ Wc, const float* __restrict__ PW,
                       unsigned short* __restrict__ WT)
{
    const int blk = blockIdx.x, t = threadIdx.x;
    if (blk < 512) {
        __shared__ float se[128];
        if (t < 128) se[t] = emb[x[blk]*128 + t];
        __syncthreads();
        if (t < 128) {
            float acc = b_node[t];
            for (int k = 0; k < 128; ++k) acc = fmaf(se[k], W_node[k*128+t], acc);
            h[blk*128+t] = acc;
        }
    } else if (blk == 512) {
        if (t < 128) {
            float wc0=0,wc1=0,wc2=0,wc3=0,wc4=0,wc5=0,bv=0;
            for (int m = 0; m < 128; ++m) {
                float we = W_ee[m*128 + t];
                wc0 = fmaf(W_ea[0*128+m], we, wc0);
                wc1 = fmaf(W_ea[1*128+m], we, wc1);
                wc2 = fmaf(W_ea[2*128+m], we, wc2);
                wc3 = fmaf(W_ea[3*128+m], we, wc3);
                wc4 = fmaf(W_ea[4*128+m], we, wc4);
                wc5 = fmaf(W_ea[5*128+m], we, wc5);
                bv  = fmaf(b_ea[m], we, bv);
            }
            Wcb[0*128+t]=wc0; Wcb[1*128+t]=wc1; Wcb[2*128+t]=wc2;
            Wcb[3*128+t]=wc3; Wcb[4*128+t]=wc4; Wcb[5*128+t]=wc5;
            bcb[t] = bv + b_ee[t];
        }
    } else {
        const int m = blk - 513;            // 0..5 = layer*2 + (0:Wc, 1:plo_W)
        const int l = m >> 1;
        const float* src = (m & 1) ? (PW + (size_t)l*16384) : (Wc + (size_t)l*16384);
        unsigned short* dst = WT + (size_t)m*16384;
        for (int idx = t; idx < 16384; idx += 256) {
            int n = idx >> 7, k = idx & 127;
            dst[idx] = f2bf(src[k*128 + n]);   // [n][k] bf16 (transposed)
        }
    }
}

// ---------------- K2: e0 init
__global__ void k_einit(const float* __restrict__ adj, const float* __restrict__ Wcb,
                        const float* __restrict__ bcb, float* __restrict__ e)
{
    __shared__ float sW[6*128];
    __shared__ float sb[128];
    int blk = blockIdx.x, t = threadIdx.x;
    int b = blk >> 8, i = blk & 255;
    for (int idx = t; idx < 768; idx += 128) sW[idx] = Wcb[idx];
    sb[t] = bcb[t];
    __syncthreads();
    const float* arow = adj + (size_t)b*393216 + (size_t)i*256;
    float* erow = e + (size_t)blk*32768;
    for (int j = 0; j < 256; ++j) {
        float a0 = arow[j];
        float a1 = arow[65536 + j];
        float a2 = arow[131072 + j];
        float a3 = arow[196608 + j];
        float a4 = arow[262144 + j];
        float a5 = arow[327680 + j];
        float v = sb[t];
        v = fmaf(a0, sW[t],     v);
        v = fmaf(a1, sW[128+t], v);
        v = fmaf(a2, sW[256+t], v);
        v = fmaf(a3, sW[384+t], v);
        v = fmaf(a4, sW[512+t], v);
        v = fmaf(a5, sW[640+t], v);
        erow[j*128 + t] = v;
    }
}

// ---------------- K3: Uh/Bh normal; Vh/Ah transposed [b][n][v]
__global__ void k_hgemm(const float* __restrict__ h,
    const float* __restrict__ Wu_l, const float* __restrict__ bu_l,
    const float* __restrict__ Wv_l, const float* __restrict__ bv_l,
    const float* __restrict__ Wa_l, const float* __restrict__ ba_l,
    const float* __restrict__ Wb_l, const float* __restrict__ bb_l,
    float* __restrict__ Uh, float* __restrict__ VhT, float* __restrict__ AhT,
    float* __restrict__ Bh)
{
    __shared__ float sh[128];
    int blk = blockIdx.x, t = threadIdx.x;
    int b = blk >> 8, v = blk & 255;
    sh[t] = h[blk*128+t];
    __syncthreads();
    float au=bu_l[t], av=bv_l[t], aa=ba_l[t], ab=bb_l[t];
    for (int k = 0; k < 128; ++k) {
        float hv = sh[k];
        au = fmaf(hv, Wu_l[k*128+t], au);
        av = fmaf(hv, Wv_l[k*128+t], av);
        aa = fmaf(hv, Wa_l[k*128+t], aa);
        ab = fmaf(hv, Wb_l[k*128+t], ab);
    }
    Uh[blk*128+t]=au; Bh[blk*128+t]=ab;
    VhT[(size_t)(b*128+t)*256 + v] = av;
    AhT[(size_t)(b*128+t)*256 + v] = aa;
}

// ---------------- K4: fused layer, wave-autonomous (each wave owns 16 rows x 128 cols per chunk)
__global__ __launch_bounds__(256) void k_layer(
    float* __restrict__ e,
    const unsigned short* __restrict__ WcT, const unsigned short* __restrict__ PWT,
    const float* __restrict__ bc_l,
    const float* __restrict__ AhT, const float* __restrict__ Bh,
    const float* __restrict__ Uh, const float* __restrict__ VhT,
    const float* __restrict__ adj, float* __restrict__ h,
    const float* __restrict__ lnh_g, const float* __restrict__ lnh_b,
    const float* __restrict__ lne_g, const float* __restrict__ lne_b,
    const float* __restrict__ plo_g, const float* __restrict__ plo_b,
    const float* __restrict__ pbW_l,
    float* __restrict__ gsum, float* __restrict__ gsq, int do_stats)
{
    __shared__ __align__(16) char sEa[4][4096];  // per-wave private bf16 [16][128] swizzled
    __shared__ float sRedA[512];
    __shared__ float sRedB[512];
    __shared__ float sred4[4];

    const int t = threadIdx.x;
    const int blk = blockIdx.x;
    const int b = blk >> 8, i = blk & 255;
    const int w = t >> 6, lane = t & 63;
    const int lane16 = lane & 15, g = lane >> 4;
    const size_t rowbase = (size_t)blk * 32768;
    char* sE = sEa[w];

    // per-lane per-column constants (cols nt*16+lane16)
    float lg[8], lb[8], pg[8], pb[8], pw[8], bcB[8];
    #pragma unroll
    for (int nt = 0; nt < 8; ++nt) {
        const int col = nt*16 + lane16;
        lg[nt] = lne_g[col]; lb[nt] = lne_b[col];
        pg[nt] = plo_g[col]; pb[nt] = plo_b[col];
        pw[nt] = pbW_l[col];
        bcB[nt] = bc_l[col] + Bh[blk*128 + col];
    }
    const float* adjm = adj + (size_t)b*393216 + (size_t)i*256;

    float agg[8], gs[8], gq[8];
    #pragma unroll
    for (int nt = 0; nt < 8; ++nt) { agg[nt]=0.f; gs[nt]=0.f; gq[nt]=0.f; }

    const int rS = lane >> 2, qS = lane & 3;

    for (int c = 0; c < 4; ++c) {
        const int j0 = c*64 + w*16;   // this wave's global row base
        // --- stage own 16 rows (fp32 global -> bf16 LDS, swizzled); wave-private
        {
            const float* src = e + rowbase + (size_t)(j0 + rS)*128 + qS*32;
            #pragma unroll
            for (int ii = 0; ii < 4; ++ii) {
                float4 f0 = *(const float4*)&src[ii*8];
                float4 f1 = *(const float4*)&src[ii*8+4];
                *(short8v*)(sE + rS*256 + SWZ(rS, qS*64 + ii*16)) = pack8(f0, f1);
            }
        }
        // --- A-frags (same-wave DS ops are in-order; no barrier needed)
        short8v a8[4];
        #pragma unroll
        for (int kst = 0; kst < 4; ++kst)
            a8[kst] = *(const short8v*)(sE + lane16*256 + SWZ(lane16, kst*64 + g*16));

        const float4 mk = *(const float4*)&adjm[j0 + g*4];
        const float* mkp = (const float*)&mk;

        // --- GEMM1: e @ Wc (per nt: 4 MFMA), epilogue: biases, gates/agg, row-stat accum
        f32x4 tv[8];
        float s1[4] = {0,0,0,0}, q1[4] = {0,0,0,0};
        #pragma unroll
        for (int nt = 0; nt < 8; ++nt) {
            const int col = nt*16 + lane16;
            f32x4 acc = {0.f,0.f,0.f,0.f};
            #pragma unroll
            for (int kst = 0; kst < 4; ++kst) {
                short8v bfr = *(const short8v*)&WcT[col*128 + kst*32 + g*8];
                acc = __builtin_amdgcn_mfma_f32_16x16x32_bf16(a8[kst], bfr, acc, 0, 0, 0);
            }
            const int jb = j0 + g*4;
            const float4 ah = *(const float4*)&AhT[(size_t)(b*128+col)*256 + jb];
            const float4 vh = *(const float4*)&VhT[(size_t)(b*128+col)*256 + jb];
            const float* ahp = (const float*)&ah;
            const float* vhp = (const float*)&vh;
            #pragma unroll
            for (int r = 0; r < 4; ++r) {
                float tvl = acc[r] + bcB[nt] + ahp[r];
                agg[nt] = fmaf(mkp[r]*sigmoidf_(tvl), vhp[r], agg[nt]);
                s1[r] += tvl; q1[r] = fmaf(tvl, tvl, q1[r]);
                tv[nt][r] = tvl;
            }
        }
        // --- row stats 1 (16-lane shfl reduce; wave-internal)
        float mu1[4], rs1[4];
        #pragma unroll
        for (int r = 0; r < 4; ++r) {
            float s = s1[r], q = q1[r];
            s += __shfl_xor(s,1); q += __shfl_xor(q,1);
            s += __shfl_xor(s,2); q += __shfl_xor(q,2);
            s += __shfl_xor(s,4); q += __shfl_xor(q,4);
            s += __shfl_xor(s,8); q += __shfl_xor(q,8);
            float mu = s*(1.f/128.f);
            mu1[r] = mu; rs1[r] = rsqrtf(q*(1.f/128.f) - mu*mu + EPSV);
        }
        // --- LN1 + relu (in place), accumulate stats 2
        float s2[4] = {0,0,0,0}, q2[4] = {0,0,0,0};
        #pragma unroll
        for (int nt = 0; nt < 8; ++nt) {
            #pragma unroll
            for (int r = 0; r < 4; ++r) {
                float tp = fmaxf(fmaf((tv[nt][r]-mu1[r])*rs1[r], lg[nt], lb[nt]), 0.f);
                tv[nt][r] = tp;
                s2[r] += tp; q2[r] = fmaf(tp, tp, q2[r]);
            }
        }
        float mu2[4], rs2[4];
        #pragma unroll
        for (int r = 0; r < 4; ++r) {
            float s = s2[r], q = q2[r];
            s += __shfl_xor(s,1); q += __shfl_xor(q,1);
            s += __shfl_xor(s,2); q += __shfl_xor(q,2);
            s += __shfl_xor(s,4); q += __shfl_xor(q,4);
            s += __shfl_xor(s,8); q += __shfl_xor(q,8);
            float mu = s*(1.f/128.f);
            mu2[r] = mu; rs2[r] = rsqrtf(q*(1.f/128.f) - mu*mu + EPSV);
        }
        // --- LN2 + silu -> Ua (bf16) into own LDS slice (overwrites Ea; GEMM1 A-frags done)
        #pragma unroll
        for (int nt = 0; nt < 8; ++nt) {
            const int col = nt*16 + lane16;
            #pragma unroll
            for (int r = 0; r < 4; ++r) {
                float u = fmaf((tv[nt][r]-mu2[r])*rs2[r], pg[nt], pb[nt]);
                u = u * sigmoidf_(u);
                const int row = g*4 + r;
                *(short*)(sE + row*256 + SWZ(row, col*2)) = (short)f2bf(u);
            }
        }
        // --- GEMM2: Ua @ plo_W; epilogue: +bias +residual, store e, GN stats
        #pragma unroll
        for (int kst = 0; kst < 4; ++kst)
            a8[kst] = *(const short8v*)(sE + lane16*256 + SWZ(lane16, kst*64 + g*16));
        #pragma unroll
        for (int nt = 0; nt < 8; ++nt) {
            const int col = nt*16 + lane16;
            f32x4 acc = {0.f,0.f,0.f,0.f};
            #pragma unroll
            for (int kst = 0; kst < 4; ++kst) {
                short8v bfr = *(const short8v*)&PWT[col*128 + kst*32 + g*8];
                acc = __builtin_amdgcn_mfma_f32_16x16x32_bf16(a8[kst], bfr, acc, 0, 0, 0);
            }
            #pragma unroll
            for (int r = 0; r < 4; ++r) {
                const int j = j0 + g*4 + r;
                float* ep = &e[rowbase + (size_t)j*128 + col];
                float o = acc[r] + pw[nt] + *ep;
                if (do_stats) { gs[nt] += o; gq[nt] = fmaf(o, o, gq[nt]); }
                *ep = o;
            }
        }
    }

    // ---- agg reduce across g-groups and waves; h update
    #pragma unroll
    for (int nt = 0; nt < 8; ++nt) {
        float a = agg[nt];
        a += __shfl_xor(a, 16); a += __shfl_xor(a, 32);
        if (lane < 16) sRedA[w*128 + nt*16 + lane] = a;
    }
    __syncthreads();
    {
        float s = 0.f, q = 0.f, val = 0.f;
        if (t < 128) {
            val = Uh[blk*128 + t] + sRedA[t] + sRedA[128+t] + sRedA[256+t] + sRedA[384+t];
            s = val; q = val*val;
            #pragma unroll
            for (int off = 32; off; off >>= 1) { s += __shfl_down(s, off); q += __shfl_down(q, off); }
            if ((t & 63) == 0) { sred4[t>>6] = s; sred4[2 + (t>>6)] = q; }
        }
        __syncthreads();
        if (t < 128) {
            s = sred4[0] + sred4[1]; q = sred4[2] + sred4[3];
            float mean = s * (1.f/128.f);
            float var  = q * (1.f/128.f) - mean*mean;
            float nv = (val - mean) * rsqrtf(var + EPSV) * lnh_g[t] + lnh_b[t];
            h[blk*128 + t] += fmaxf(nv, 0.f);
        }
    }
    // ---- GroupNorm channel partial sums (last layer only)
    if (do_stats) {
        __syncthreads();
        #pragma unroll
        for (int nt = 0; nt < 8; ++nt) {
            float a = gs[nt], qq = gq[nt];
            a  += __shfl_xor(a, 16);  a  += __shfl_xor(a, 32);
            qq += __shfl_xor(qq, 16); qq += __shfl_xor(qq, 32);
            if (lane < 16) { sRedA[w*128 + nt*16 + lane] = a; sRedB[w*128 + nt*16 + lane] = qq; }
        }
        __syncthreads();
        if (t < 128) {
            float S = sRedA[t] + sRedA[128+t] + sRedA[256+t] + sRedA[384+t];
            float Q = sRedB[t] + sRedB[128+t] + sRedB[256+t] + sRedB[384+t];
            atomicAdd(&gsum[b*128 + t], S);
            atomicAdd(&gsq[b*128 + t], Q);
        }
    }
}

// ---------------- K7: finalize group stats
__global__ void k_gfin(const float* __restrict__ gsum, const float* __restrict__ gsq,
                       float* __restrict__ gmu, float* __restrict__ grs)
{
    int t = threadIdx.x; // 64
    int b = t >> 5, g = t & 31;
    int base = b*128 + g*4;
    float s = gsum[base]+gsum[base+1]+gsum[base+2]+gsum[base+3];
    float q = gsq[base]+gsq[base+1]+gsq[base+2]+gsq[base+3];
    const float invN = 1.f/(4.f*65536.f);
    float mu = s*invN;
    float var = q*invN - mu*mu;
    gmu[t] = mu;
    grs[t] = rsqrtf(var + EPSV);
}

// ---------------- K8: head: GN transform -> relu -> 1x1 conv (dot over 128 ch)
__global__ void k_head(const float* __restrict__ e, const float* __restrict__ gmu,
                       const float* __restrict__ grs, const float* __restrict__ gn_g,
                       const float* __restrict__ gn_b, const float* __restrict__ W_out,
                       const float* __restrict__ b_out, float* __restrict__ out)
{
    int blk = blockIdx.x, t = threadIdx.x;
    int b = blk >> 8;
    int w = t >> 6, lane = t & 63;
    int c0 = lane, c1 = lane + 64;
    float mu0 = gmu[b*32 + (c0>>2)], rs0 = grs[b*32 + (c0>>2)];
    float mu1 = gmu[b*32 + (c1>>2)], rs1 = grs[b*32 + (c1>>2)];
    float gg0 = gn_g[c0]*rs0, gb0 = gn_b[c0] - mu0*gg0;
    float gg1 = gn_g[c1]*rs1, gb1 = gn_b[c1] - mu1*gg1;
    float wo0 = W_out[c0], wo1 = W_out[c1];
    float bo = b_out[0];
    const float* erow = e + (size_t)blk*32768;
    float* orow = out + (size_t)blk*256;
    for (int jj = 0; jj < 64; ++jj) {
        int j = w*64 + jj;
        float v0 = erow[(size_t)j*128 + c0];
        float v1 = erow[(size_t)j*128 + c1];
        float r = fmaxf(fmaf(v0, gg0, gb0), 0.f)*wo0 + fmaxf(fmaf(v1, gg1, gb1), 0.f)*wo1;
        #pragma unroll
        for (int off = 32; off; off >>= 1) r += __shfl_down(r, off);
        if (lane == 0) orow[j] = r + bo;
    }
}

extern "C" void kernel_launch(void* const* d_in, const int* in_sizes, int n_in,
                              void* d_out, int out_size, void* d_ws, size_t ws_size,
                              hipStream_t stream)
{
    const int*   x      = (const int*)  d_in[0];
    const float* adj    = (const float*)d_in[1];
    const float* emb    = (const float*)d_in[2];
    const float* W_node = (const float*)d_in[3];
    const float* b_node = (const float*)d_in[4];
    const float* W_ea   = (const float*)d_in[5];
    const float* b_ea   = (const float*)d_in[6];
    const float* W_ee   = (const float*)d_in[7];
    const float* b_ee   = (const float*)d_in[8];
    const float* Wu     = (const float*)d_in[9];
    const float* bu     = (const float*)d_in[10];
    const float* Wv     = (const float*)d_in[11];
    const float* bv     = (const float*)d_in[12];
    const float* Wa     = (const float*)d_in[13];
    const float* ba     = (const float*)d_in[14];
    const float* Wb     = (const float*)d_in[15];
    const float* bb     = (const float*)d_in[16];
    const float* Wc     = (const float*)d_in[17];
    const float* bc     = (const float*)d_in[18];
    const float* lnh_g  = (const float*)d_in[19];
    const float* lnh_b  = (const float*)d_in[20];
    const float* lne_g  = (const float*)d_in[21];
    const float* lne_b  = (const float*)d_in[22];
    const float* plo_g  = (const float*)d_in[23];
    const float* plo_b  = (const float*)d_in[24];
    const float* plo_W  = (const float*)d_in[25];
    const float* plo_bW = (const float*)d_in[26];
    const float* gn_g   = (const float*)d_in[27];
    const float* gn_b   = (const float*)d_in[28];
    const float* W_out  = (const float*)d_in[29];
    const float* b_out  = (const float*)d_in[30];
    float* out = (float*)d_out;

    float* ws = (float*)d_ws;
    size_t off = 0;
    float* e    = ws + off; off += (size_t)2*256*256*128;  // 67 MB
    float* h    = ws + off; off += 65536;
    float* Uh   = ws + off; off += 65536;
    float* Bh   = ws + off; off += 65536;
    float* VhT  = ws + off; off += 65536;
    float* AhT  = ws + off; off += 65536;
    float* Wcb  = ws + off; off += 768;
    float* bcb  = ws + off; off += 128;
    float* gsum = ws + off; off += 256;
    float* gsq  = ws + off; off += 256;   // contiguous with gsum
    float* gmu  = ws + off; off += 64;
    float* grs  = ws + off; off += 64;
    unsigned short* WT = (unsigned short*)(ws + off); off += 49152;  // 6 x 128x128 bf16

    k_prep<<<519, 256, 0, stream>>>(x, emb, W_node, b_node, h,
                                    W_ea, b_ea, W_ee, b_ee, Wcb, bcb,
                                    Wc, plo_W, WT);
    k_einit<<<512, 128, 0, stream>>>(adj, Wcb, bcb, e);
    hipMemsetAsync(gsum, 0, 512*sizeof(float), stream);

    for (int l = 0; l < 3; ++l) {
        k_hgemm<<<512, 128, 0, stream>>>(h,
            Wu + (size_t)l*16384, bu + l*128,
            Wv + (size_t)l*16384, bv + l*128,
            Wa + (size_t)l*16384, ba + l*128,
            Wb + (size_t)l*16384, bb + l*128,
            Uh, VhT, AhT, Bh);
        k_layer<<<512, 256, 0, stream>>>(e,
            WT + (size_t)(2*l)*16384, WT + (size_t)(2*l+1)*16384,
            bc + l*128,
            AhT, Bh, Uh, VhT, adj, h,
            lnh_g + l*128, lnh_b + l*128,
            lne_g + l*128, lne_b + l*128,
            plo_g + l*128, plo_b + l*128,
            plo_bW + l*128,
            gsum, gsq, (l == 2) ? 1 : 0);
    }

    k_gfin<<<1, 64, 0, stream>>>(gsum, gsq, gmu, grs);
    k_head<<<512, 256, 0, stream>>>(e, gmu, grs, gn_g, gn_b, W_out, b_out, out);
}

// Round 4
// 407.366 us; speedup vs baseline: 2.6141x; 1.1658x over previous
//
#include <hip/hip_runtime.h>
#include <cstdint>
#include <cstddef>

// GNNDi: B=2, V=256, H=128, L=3, GroupNorm32 head. e stored [b][i][j][h] fp32.

#define EPSV 1e-5f

typedef __attribute__((ext_vector_type(8))) short short8v;  // 8 bf16
typedef __attribute__((ext_vector_type(4))) float f32x4;

__device__ __forceinline__ float sigmoidf_(float x) { return 1.f / (1.f + __expf(-x)); }

__device__ __forceinline__ unsigned short f2bf(float x) {
    unsigned int u = __float_as_uint(x);
    unsigned int r = u + 0x7FFFu + ((u >> 16) & 1u);   // RNE
    return (unsigned short)(r >> 16);
}
__device__ __forceinline__ short8v pack8(float4 a, float4 b) {
    short8v r;
    r[0]=(short)f2bf(a.x); r[1]=(short)f2bf(a.y); r[2]=(short)f2bf(a.z); r[3]=(short)f2bf(a.w);
    r[4]=(short)f2bf(b.x); r[5]=(short)f2bf(b.y); r[6]=(short)f2bf(b.z); r[7]=(short)f2bf(b.w);
    return r;
}
#define SWZ(row, cb) ((cb) ^ (((row) & 7) << 4))

// ---------------- K_prep: node embed + aggB zero (blocks 0..511), wcomb (512), weight transpose (513..518)
__global__ void k_prep(const int* __restrict__ x, const float* __restrict__ emb,
                       const float* __restrict__ W_node, const float* __restrict__ b_node,
                       float* __restrict__ h, float* __restrict__ aggB,
                       const float* __restrict__ W_ea, const float* __restrict__ b_ea,
                       const float* __restrict__ W_ee, const float* __restrict__ b_ee,
                       float* __restrict__ Wcb, float* __restrict__ bcb,
                       const float* __restrict__ Wc, const float* __restrict__ PW,
                       unsigned short* __restrict__ WT)
{
    const int blk = blockIdx.x, t = threadIdx.x;
    if (blk < 512) {
        __shared__ float se[128];
        if (t < 128) { se[t] = emb[x[blk]*128 + t]; aggB[blk*128 + t] = 0.f; }
        __syncthreads();
        if (t < 128) {
            float acc = b_node[t];
            for (int k = 0; k < 128; ++k) acc = fmaf(se[k], W_node[k*128+t], acc);
            h[blk*128+t] = acc;
        }
    } else if (blk == 512) {
        if (t < 128) {
            float wc0=0,wc1=0,wc2=0,wc3=0,wc4=0,wc5=0,bv=0;
            for (int m = 0; m < 128; ++m) {
                float we = W_ee[m*128 + t];
                wc0 = fmaf(W_ea[0*128+m], we, wc0);
                wc1 = fmaf(W_ea[1*128+m], we, wc1);
                wc2 = fmaf(W_ea[2*128+m], we, wc2);
                wc3 = fmaf(W_ea[3*128+m], we, wc3);
                wc4 = fmaf(W_ea[4*128+m], we, wc4);
                wc5 = fmaf(W_ea[5*128+m], we, wc5);
                bv  = fmaf(b_ea[m], we, bv);
            }
            Wcb[0*128+t]=wc0; Wcb[1*128+t]=wc1; Wcb[2*128+t]=wc2;
            Wcb[3*128+t]=wc3; Wcb[4*128+t]=wc4; Wcb[5*128+t]=wc5;
            bcb[t] = bv + b_ee[t];
        }
    } else {
        const int m = blk - 513;            // 0..5 = layer*2 + (0:Wc, 1:plo_W)
        const int l = m >> 1;
        const float* src = (m & 1) ? (PW + (size_t)l*16384) : (Wc + (size_t)l*16384);
        unsigned short* dst = WT + (size_t)m*16384;
        for (int idx = t; idx < 16384; idx += 256) {
            int n = idx >> 7, k = idx & 127;
            dst[idx] = f2bf(src[k*128 + n]);   // [n][k] bf16 (transposed)
        }
    }
}

// ---------------- K2: e0 init
__global__ void k_einit(const float* __restrict__ adj, const float* __restrict__ Wcb,
                        const float* __restrict__ bcb, float* __restrict__ e)
{
    __shared__ float sW[6*128];
    __shared__ float sb[128];
    int blk = blockIdx.x, t = threadIdx.x;
    int b = blk >> 8, i = blk & 255;
    for (int idx = t; idx < 768; idx += 128) sW[idx] = Wcb[idx];
    sb[t] = bcb[t];
    __syncthreads();
    const float* arow = adj + (size_t)b*393216 + (size_t)i*256;
    float* erow = e + (size_t)blk*32768;
    for (int j = 0; j < 256; ++j) {
        float a0 = arow[j];
        float a1 = arow[65536 + j];
        float a2 = arow[131072 + j];
        float a3 = arow[196608 + j];
        float a4 = arow[262144 + j];
        float a5 = arow[327680 + j];
        float v = sb[t];
        v = fmaf(a0, sW[t],     v);
        v = fmaf(a1, sW[128+t], v);
        v = fmaf(a2, sW[256+t], v);
        v = fmaf(a3, sW[384+t], v);
        v = fmaf(a4, sW[512+t], v);
        v = fmaf(a5, sW[640+t], v);
        erow[j*128 + t] = v;
    }
}

// ---------------- K3: fused h-update (from prev layer) + 4 h-GEMMs; zeroes aggB
__global__ void k_hgemm(float* __restrict__ h, float* __restrict__ Uh, float* __restrict__ aggB,
    const float* __restrict__ Wu_l, const float* __restrict__ bu_l,
    const float* __restrict__ Wv_l, const float* __restrict__ bv_l,
    const float* __restrict__ Wa_l, const float* __restrict__ ba_l,
    const float* __restrict__ Wb_l, const float* __restrict__ bb_l,
    float* __restrict__ VhT, float* __restrict__ AhT, float* __restrict__ Bh,
    const float* __restrict__ lnh_g, const float* __restrict__ lnh_b, int upd)
{
    __shared__ float sh[128];
    __shared__ float sred[4];
    int blk = blockIdx.x, t = threadIdx.x;
    int b = blk >> 8, v = blk & 255;
    float hv_ = h[blk*128 + t];
    if (upd) {
        float val = Uh[blk*128 + t] + aggB[blk*128 + t];
        aggB[blk*128 + t] = 0.f;
        float s = val, q = val*val;
        #pragma unroll
        for (int off = 32; off; off >>= 1) { s += __shfl_down(s, off); q += __shfl_down(q, off); }
        if ((t & 63) == 0) { sred[t>>6] = s; sred[2 + (t>>6)] = q; }
        __syncthreads();
        s = sred[0] + sred[1]; q = sred[2] + sred[3];
        float mean = s * (1.f/128.f);
        float var  = q * (1.f/128.f) - mean*mean;
        float nv = (val - mean) * rsqrtf(var + EPSV) * lnh_g[t] + lnh_b[t];
        hv_ += fmaxf(nv, 0.f);
        h[blk*128 + t] = hv_;
    }
    sh[t] = hv_;
    __syncthreads();
    float au=bu_l[t], av=bv_l[t], aa=ba_l[t], ab=bb_l[t];
    for (int k = 0; k < 128; ++k) {
        float hv = sh[k];
        au = fmaf(hv, Wu_l[k*128+t], au);
        av = fmaf(hv, Wv_l[k*128+t], av);
        aa = fmaf(hv, Wa_l[k*128+t], aa);
        ab = fmaf(hv, Wb_l[k*128+t], ab);
    }
    Uh[blk*128+t]=au; Bh[blk*128+t]=ab;
    VhT[(size_t)(b*128+t)*256 + v] = av;
    AhT[(size_t)(b*128+t)*256 + v] = aa;
}

// ---------------- K4: fused layer chunk. grid = 512 (b,i) x 4 chunks; each wave owns 16 rows.
template<int DO_AGG, int DO_STATS>
__global__ __launch_bounds__(256) void k_layer(
    float* __restrict__ e,
    const unsigned short* __restrict__ WcT, const unsigned short* __restrict__ PWT,
    const float* __restrict__ bc_l,
    const float* __restrict__ AhT, const float* __restrict__ Bh,
    const float* __restrict__ VhT, const float* __restrict__ adj,
    const float* __restrict__ lne_g, const float* __restrict__ lne_b,
    const float* __restrict__ plo_g, const float* __restrict__ plo_b,
    const float* __restrict__ pbW_l,
    float* __restrict__ aggB, float* __restrict__ gsum, float* __restrict__ gsq)
{
    __shared__ __align__(16) char sUa[4][4096];  // per-wave private bf16 [16][128] swizzled
    __shared__ float sRedA[512];
    __shared__ float sRedB[512];

    const int t = threadIdx.x;
    const int bi = blockIdx.x >> 2, chunk = blockIdx.x & 3;
    const int b = bi >> 8, i = bi & 255;
    const int w = t >> 6, lane = t & 63;
    const int lane16 = lane & 15, g = lane >> 4;
    const size_t rowbase = (size_t)bi * 32768;
    const int j0 = chunk*64 + w*16;
    char* sE = sUa[w];

    // --- GEMM1 A-frags: direct global -> regs (row j0+lane16, k-slice g*8 per kst)
    short8v a8[4];
    {
        const float* arow = e + rowbase + (size_t)(j0 + lane16)*128 + g*8;
        #pragma unroll
        for (int kst = 0; kst < 4; ++kst) {
            float4 f0 = *(const float4*)&arow[kst*32];
            float4 f1 = *(const float4*)&arow[kst*32 + 4];
            a8[kst] = pack8(f0, f1);
        }
    }

    // --- GEMM1: e @ Wc + epilogue
    f32x4 tv[8];
    float agg[8];
    float s1[4] = {0,0,0,0}, q1[4] = {0,0,0,0};
    const int jb = j0 + g*4;
    float4 mk;
    if (DO_AGG) mk = *(const float4*)&adj[(size_t)b*393216 + (size_t)i*256 + jb];
    const float* mkp = (const float*)&mk;
    #pragma unroll
    for (int nt = 0; nt < 8; ++nt) {
        const int col = nt*16 + lane16;
        f32x4 acc = {0.f,0.f,0.f,0.f};
        #pragma unroll
        for (int kst = 0; kst < 4; ++kst) {
            short8v bfr = *(const short8v*)&WcT[col*128 + kst*32 + g*8];
            acc = __builtin_amdgcn_mfma_f32_16x16x32_bf16(a8[kst], bfr, acc, 0, 0, 0);
        }
        const float bcB = bc_l[col] + Bh[bi*128 + col];
        const float4 ah = *(const float4*)&AhT[(size_t)(b*128+col)*256 + jb];
        const float* ahp = (const float*)&ah;
        if (DO_AGG) {
            const float4 vh = *(const float4*)&VhT[(size_t)(b*128+col)*256 + jb];
            const float* vhp = (const float*)&vh;
            float a = 0.f;
            #pragma unroll
            for (int r = 0; r < 4; ++r) {
                float tvl = acc[r] + bcB + ahp[r];
                a = fmaf(mkp[r]*sigmoidf_(tvl), vhp[r], a);
                s1[r] += tvl; q1[r] = fmaf(tvl, tvl, q1[r]);
                tv[nt][r] = tvl;
            }
            agg[nt] = a;
        } else {
            #pragma unroll
            for (int r = 0; r < 4; ++r) {
                float tvl = acc[r] + bcB + ahp[r];
                s1[r] += tvl; q1[r] = fmaf(tvl, tvl, q1[r]);
                tv[nt][r] = tvl;
            }
        }
    }
    // --- row stats 1 (wave-internal 16-lane reduce)
    float mu1[4], rs1[4];
    #pragma unroll
    for (int r = 0; r < 4; ++r) {
        float s = s1[r], q = q1[r];
        s += __shfl_xor(s,1); q += __shfl_xor(q,1);
        s += __shfl_xor(s,2); q += __shfl_xor(q,2);
        s += __shfl_xor(s,4); q += __shfl_xor(q,4);
        s += __shfl_xor(s,8); q += __shfl_xor(q,8);
        float mu = s*(1.f/128.f);
        mu1[r] = mu; rs1[r] = rsqrtf(q*(1.f/128.f) - mu*mu + EPSV);
    }
    // --- LN1 + relu, stats 2
    float s2[4] = {0,0,0,0}, q2[4] = {0,0,0,0};
    #pragma unroll
    for (int nt = 0; nt < 8; ++nt) {
        const int col = nt*16 + lane16;
        const float lg = lne_g[col], lb = lne_b[col];
        #pragma unroll
        for (int r = 0; r < 4; ++r) {
            float tp = fmaxf(fmaf((tv[nt][r]-mu1[r])*rs1[r], lg, lb), 0.f);
            tv[nt][r] = tp;
            s2[r] += tp; q2[r] = fmaf(tp, tp, q2[r]);
        }
    }
    float mu2[4], rs2[4];
    #pragma unroll
    for (int r = 0; r < 4; ++r) {
        float s = s2[r], q = q2[r];
        s += __shfl_xor(s,1); q += __shfl_xor(q,1);
        s += __shfl_xor(s,2); q += __shfl_xor(q,2);
        s += __shfl_xor(s,4); q += __shfl_xor(q,4);
        s += __shfl_xor(s,8); q += __shfl_xor(q,8);
        float mu = s*(1.f/128.f);
        mu2[r] = mu; rs2[r] = rsqrtf(q*(1.f/128.f) - mu*mu + EPSV);
    }
    // --- LN2 + silu -> Ua bf16 into wave-private LDS (transpose for GEMM2 A)
    #pragma unroll
    for (int nt = 0; nt < 8; ++nt) {
        const int col = nt*16 + lane16;
        const float pg = plo_g[col], pb = plo_b[col];
        #pragma unroll
        for (int r = 0; r < 4; ++r) {
            float u = fmaf((tv[nt][r]-mu2[r])*rs2[r], pg, pb);
            u = u * sigmoidf_(u);
            const int row = g*4 + r;
            *(short*)(sE + row*256 + SWZ(row, col*2)) = (short)f2bf(u);
        }
    }
    // --- GEMM2: Ua @ plo_W + residual; GN stats
    #pragma unroll
    for (int kst = 0; kst < 4; ++kst)
        a8[kst] = *(const short8v*)(sE + lane16*256 + SWZ(lane16, kst*64 + g*16));
    float gs[8], gq[8];
    #pragma unroll
    for (int nt = 0; nt < 8; ++nt) {
        const int col = nt*16 + lane16;
        f32x4 acc = {0.f,0.f,0.f,0.f};
        #pragma unroll
        for (int kst = 0; kst < 4; ++kst) {
            short8v bfr = *(const short8v*)&PWT[col*128 + kst*32 + g*8];
            acc = __builtin_amdgcn_mfma_f32_16x16x32_bf16(a8[kst], bfr, acc, 0, 0, 0);
        }
        const float pw = pbW_l[col];
        float gsl = 0.f, gql = 0.f;
        #pragma unroll
        for (int r = 0; r < 4; ++r) {
            const int j = j0 + g*4 + r;
            float* ep = &e[rowbase + (size_t)j*128 + col];
            float o = acc[r] + pw + *ep;
            if (DO_STATS) { gsl += o; gql = fmaf(o, o, gql); }
            *ep = o;
        }
        gs[nt] = gsl; gq[nt] = gql;
    }

    // ---- block tails
    if (DO_AGG) {
        #pragma unroll
        for (int nt = 0; nt < 8; ++nt) {
            float a = agg[nt];
            a += __shfl_xor(a, 16); a += __shfl_xor(a, 32);
            if (lane < 16) sRedA[w*128 + nt*16 + lane] = a;
        }
        __syncthreads();
        if (t < 128) {
            float S = sRedA[t] + sRedA[128+t] + sRedA[256+t] + sRedA[384+t];
            atomicAdd(&aggB[bi*128 + t], S);
        }
    }
    if (DO_STATS) {
        #pragma unroll
        for (int nt = 0; nt < 8; ++nt) {
            float a = gs[nt], qq = gq[nt];
            a  += __shfl_xor(a, 16);  a  += __shfl_xor(a, 32);
            qq += __shfl_xor(qq, 16); qq += __shfl_xor(qq, 32);
            if (lane < 16) { sRedA[w*128 + nt*16 + lane] = a; sRedB[w*128 + nt*16 + lane] = qq; }
        }
        __syncthreads();
        if (t < 128) {
            float S = sRedA[t] + sRedA[128+t] + sRedA[256+t] + sRedA[384+t];
            float Q = sRedB[t] + sRedB[128+t] + sRedB[256+t] + sRedB[384+t];
            atomicAdd(&gsum[b*128 + t], S);
            atomicAdd(&gsq[b*128 + t], Q);
        }
    }
}

// ---------------- K7: finalize group stats
__global__ void k_gfin(const float* __restrict__ gsum, const float* __restrict__ gsq,
                       float* __restrict__ gmu, float* __restrict__ grs)
{
    int t = threadIdx.x; // 64
    int b = t >> 5, g = t & 31;
    int base = b*128 + g*4;
    float s = gsum[base]+gsum[base+1]+gsum[base+2]+gsum[base+3];
    float q = gsq[base]+gsq[base+1]+gsq[base+2]+gsq[base+3];
    const float invN = 1.f/(4.f*65536.f);
    float mu = s*invN;
    float var = q*invN - mu*mu;
    gmu[t] = mu;
    grs[t] = rsqrtf(var + EPSV);
}

// ---------------- K8: head: GN transform -> relu -> 1x1 conv (dot over 128 ch)
__global__ void k_head(const float* __restrict__ e, const float* __restrict__ gmu,
                       const float* __restrict__ grs, const float* __restrict__ gn_g,
                       const float* __restrict__ gn_b, const float* __restrict__ W_out,
                       const float* __restrict__ b_out, float* __restrict__ out)
{
    int blk = blockIdx.x, t = threadIdx.x;
    int b = blk >> 8;
    int w = t >> 6, lane = t & 63;
    int c0 = lane, c1 = lane + 64;
    float mu0 = gmu[b*32 + (c0>>2)], rs0 = grs[b*32 + (c0>>2)];
    float mu1 = gmu[b*32 + (c1>>2)], rs1 = grs[b*32 + (c1>>2)];
    float gg0 = gn_g[c0]*rs0, gb0 = gn_b[c0] - mu0*gg0;
    float gg1 = gn_g[c1]*rs1, gb1 = gn_b[c1] - mu1*gg1;
    float wo0 = W_out[c0], wo1 = W_out[c1];
    float bo = b_out[0];
    const float* erow = e + (size_t)blk*32768;
    float* orow = out + (size_t)blk*256;
    for (int jj = 0; jj < 64; ++jj) {
        int j = w*64 + jj;
        float v0 = erow[(size_t)j*128 + c0];
        float v1 = erow[(size_t)j*128 + c1];
        float r = fmaxf(fmaf(v0, gg0, gb0), 0.f)*wo0 + fmaxf(fmaf(v1, gg1, gb1), 0.f)*wo1;
        #pragma unroll
        for (int off = 32; off; off >>= 1) r += __shfl_down(r, off);
        if (lane == 0) orow[j] = r + bo;
    }
}

extern "C" void kernel_launch(void* const* d_in, const int* in_sizes, int n_in,
                              void* d_out, int out_size, void* d_ws, size_t ws_size,
                              hipStream_t stream)
{
    const int*   x      = (const int*)  d_in[0];
    const float* adj    = (const float*)d_in[1];
    const float* emb    = (const float*)d_in[2];
    const float* W_node = (const float*)d_in[3];
    const float* b_node = (const float*)d_in[4];
    const float* W_ea   = (const float*)d_in[5];
    const float* b_ea   = (const float*)d_in[6];
    const float* W_ee   = (const float*)d_in[7];
    const float* b_ee   = (const float*)d_in[8];
    const float* Wu     = (const float*)d_in[9];
    const float* bu     = (const float*)d_in[10];
    const float* Wv     = (const float*)d_in[11];
    const float* bv     = (const float*)d_in[12];
    const float* Wa     = (const float*)d_in[13];
    const float* ba     = (const float*)d_in[14];
    const float* Wb     = (const float*)d_in[15];
    const float* bb     = (const float*)d_in[16];
    const float* Wc     = (const float*)d_in[17];
    const float* bc     = (const float*)d_in[18];
    const float* lnh_g  = (const float*)d_in[19];
    const float* lnh_b  = (const float*)d_in[20];
    const float* lne_g  = (const float*)d_in[21];
    const float* lne_b  = (const float*)d_in[22];
    const float* plo_g  = (const float*)d_in[23];
    const float* plo_b  = (const float*)d_in[24];
    const float* plo_W  = (const float*)d_in[25];
    const float* plo_bW = (const float*)d_in[26];
    const float* gn_g   = (const float*)d_in[27];
    const float* gn_b   = (const float*)d_in[28];
    const float* W_out  = (const float*)d_in[29];
    const float* b_out  = (const float*)d_in[30];
    float* out = (float*)d_out;

    float* ws = (float*)d_ws;
    size_t off = 0;
    float* e    = ws + off; off += (size_t)2*256*256*128;  // 67 MB
    float* h    = ws + off; off += 65536;
    float* Uh   = ws + off; off += 65536;
    float* Bh   = ws + off; off += 65536;
    float* VhT  = ws + off; off += 65536;
    float* AhT  = ws + off; off += 65536;
    float* aggB = ws + off; off += 65536;
    float* Wcb  = ws + off; off += 768;
    float* bcb  = ws + off; off += 128;
    float* gsum = ws + off; off += 256;
    float* gsq  = ws + off; off += 256;   // contiguous with gsum
    float* gmu  = ws + off; off += 64;
    float* grs  = ws + off; off += 64;
    unsigned short* WT = (unsigned short*)(ws + off); off += 49152;  // 6 x 128x128 bf16

    k_prep<<<519, 256, 0, stream>>>(x, emb, W_node, b_node, h, aggB,
                                    W_ea, b_ea, W_ee, b_ee, Wcb, bcb,
                                    Wc, plo_W, WT);
    k_einit<<<512, 128, 0, stream>>>(adj, Wcb, bcb, e);
    hipMemsetAsync(gsum, 0, 512*sizeof(float), stream);

    for (int l = 0; l < 3; ++l) {
        k_hgemm<<<512, 128, 0, stream>>>(h, Uh, aggB,
            Wu + (size_t)l*16384, bu + l*128,
            Wv + (size_t)l*16384, bv + l*128,
            Wa + (size_t)l*16384, ba + l*128,
            Wb + (size_t)l*16384, bb + l*128,
            VhT, AhT, Bh,
            lnh_g + (l==0?0:(l-1)*128), lnh_b + (l==0?0:(l-1)*128), l > 0 ? 1 : 0);
        if (l < 2) {
            k_layer<1,0><<<2048, 256, 0, stream>>>(e,
                WT + (size_t)(2*l)*16384, WT + (size_t)(2*l+1)*16384,
                bc + l*128, AhT, Bh, VhT, adj,
                lne_g + l*128, lne_b + l*128,
                plo_g + l*128, plo_b + l*128,
                plo_bW + l*128, aggB, gsum, gsq);
        } else {
            k_layer<0,1><<<2048, 256, 0, stream>>>(e,
                WT + (size_t)(2*l)*16384, WT + (size_t)(2*l+1)*16384,
                bc + l*128, AhT, Bh, VhT, adj,
                lne_g + l*128, lne_b + l*128,
                plo_g + l*128, plo_b + l*128,
                plo_bW + l*128, aggB, gsum, gsq);
        }
    }

    k_gfin<<<1, 64, 0, stream>>>(gsum, gsq, gmu, grs);
    k_head<<<512, 256, 0, stream>>>(e, gmu, grs, gn_g, gn_b, W_out, b_out, out);
}

// Round 5
// 366.194 us; speedup vs baseline: 2.9080x; 1.1124x over previous
//
#include <hip/hip_runtime.h>
#include <cstdint>
#include <cstddef>

// GNNDi: B=2, V=256, H=128, L=3, GroupNorm32 head. e stored [b][i][j][h] bf16.

#define EPSV 1e-5f

typedef __attribute__((ext_vector_type(8))) short short8v;  // 8 bf16
typedef __attribute__((ext_vector_type(4))) float f32x4;

__device__ __forceinline__ float sigmoidf_(float x) { return 1.f / (1.f + __expf(-x)); }

__device__ __forceinline__ unsigned short f2bf(float x) {
    unsigned int u = __float_as_uint(x);
    unsigned int r = u + 0x7FFFu + ((u >> 16) & 1u);   // RNE
    return (unsigned short)(r >> 16);
}
__device__ __forceinline__ float bf2f(unsigned short u) {
    return __uint_as_float(((unsigned int)u) << 16);
}
#define SWZ(row, cb) ((cb) ^ (((row) & 7) << 4))

// ---------------- K_prep: node embed + aggB zero (blocks 0..511), wcomb (512), weight transpose (513..518)
__global__ void k_prep(const int* __restrict__ x, const float* __restrict__ emb,
                       const float* __restrict__ W_node, const float* __restrict__ b_node,
                       float* __restrict__ h, float* __restrict__ aggB,
                       const float* __restrict__ W_ea, const float* __restrict__ b_ea,
                       const float* __restrict__ W_ee, const float* __restrict__ b_ee,
                       float* __restrict__ Wcb, float* __restrict__ bcb,
                       const float* __restrict__ Wc, const float* __restrict__ PW,
                       unsigned short* __restrict__ WT)
{
    const int blk = blockIdx.x, t = threadIdx.x;
    if (blk < 512) {
        __shared__ float se[128];
        if (t < 128) { se[t] = emb[x[blk]*128 + t]; aggB[blk*128 + t] = 0.f; }
        __syncthreads();
        if (t < 128) {
            float acc = b_node[t];
            for (int k = 0; k < 128; ++k) acc = fmaf(se[k], W_node[k*128+t], acc);
            h[blk*128+t] = acc;
        }
    } else if (blk == 512) {
        if (t < 128) {
            float wc0=0,wc1=0,wc2=0,wc3=0,wc4=0,wc5=0,bv=0;
            for (int m = 0; m < 128; ++m) {
                float we = W_ee[m*128 + t];
                wc0 = fmaf(W_ea[0*128+m], we, wc0);
                wc1 = fmaf(W_ea[1*128+m], we, wc1);
                wc2 = fmaf(W_ea[2*128+m], we, wc2);
                wc3 = fmaf(W_ea[3*128+m], we, wc3);
                wc4 = fmaf(W_ea[4*128+m], we, wc4);
                wc5 = fmaf(W_ea[5*128+m], we, wc5);
                bv  = fmaf(b_ea[m], we, bv);
            }
            Wcb[0*128+t]=wc0; Wcb[1*128+t]=wc1; Wcb[2*128+t]=wc2;
            Wcb[3*128+t]=wc3; Wcb[4*128+t]=wc4; Wcb[5*128+t]=wc5;
            bcb[t] = bv + b_ee[t];
        }
    } else {
        const int m = blk - 513;            // 0..5 = layer*2 + (0:Wc, 1:plo_W)
        const int l = m >> 1;
        const float* src = (m & 1) ? (PW + (size_t)l*16384) : (Wc + (size_t)l*16384);
        unsigned short* dst = WT + (size_t)m*16384;
        for (int idx = t; idx < 16384; idx += 256) {
            int n = idx >> 7, k = idx & 127;
            dst[idx] = f2bf(src[k*128 + n]);   // [n][k] bf16 (transposed)
        }
    }
}

// ---------------- K2: e0 init (bf16 out, vectorized)
__global__ __launch_bounds__(256) void k_einit(
    const float* __restrict__ adj, const float* __restrict__ Wcb,
    const float* __restrict__ bcb, unsigned short* __restrict__ e)
{
    __shared__ float sAdj[6*256];
    const int blk = blockIdx.x, t = threadIdx.x;
    const int b = blk >> 8, i = blk & 255;
    const float* arow = adj + (size_t)b*393216 + (size_t)i*256;
    for (int idx = t; idx < 1536; idx += 256)
        sAdj[idx] = arow[(idx >> 8)*65536 + (idx & 255)];
    const int ch8 = (t & 15) * 8, jgrp = t >> 4;
    float w[6][8], bb8[8];
    #pragma unroll
    for (int c = 0; c < 8; ++c) bb8[c] = bcb[ch8 + c];
    #pragma unroll
    for (int m = 0; m < 6; ++m)
        #pragma unroll
        for (int c = 0; c < 8; ++c) w[m][c] = Wcb[m*128 + ch8 + c];
    __syncthreads();
    unsigned short* erow = e + (size_t)blk*32768;
    for (int it = 0; it < 16; ++it) {
        const int j = jgrp*16 + it;
        float a[6];
        #pragma unroll
        for (int m = 0; m < 6; ++m) a[m] = sAdj[m*256 + j];
        short8v o;
        #pragma unroll
        for (int c = 0; c < 8; ++c) {
            float v = bb8[c];
            #pragma unroll
            for (int m = 0; m < 6; ++m) v = fmaf(a[m], w[m][c], v);
            o[c] = (short)f2bf(v);
        }
        *(short8v*)&erow[(size_t)j*128 + ch8] = o;
    }
}

// ---------------- K3: fused h-update (from prev layer) + 4 h-GEMMs; zeroes aggB
__global__ void k_hgemm(float* __restrict__ h, float* __restrict__ Uh, float* __restrict__ aggB,
    const float* __restrict__ Wu_l, const float* __restrict__ bu_l,
    const float* __restrict__ Wv_l, const float* __restrict__ bv_l,
    const float* __restrict__ Wa_l, const float* __restrict__ ba_l,
    const float* __restrict__ Wb_l, const float* __restrict__ bb_l,
    float* __restrict__ VhT, float* __restrict__ AhT, float* __restrict__ Bh,
    const float* __restrict__ lnh_g, const float* __restrict__ lnh_b, int upd)
{
    __shared__ float sh[128];
    __shared__ float sred[4];
    int blk = blockIdx.x, t = threadIdx.x;
    int b = blk >> 8, v = blk & 255;
    float hv_ = h[blk*128 + t];
    if (upd) {
        float val = Uh[blk*128 + t] + aggB[blk*128 + t];
        aggB[blk*128 + t] = 0.f;
        float s = val, q = val*val;
        #pragma unroll
        for (int off = 32; off; off >>= 1) { s += __shfl_down(s, off); q += __shfl_down(q, off); }
        if ((t & 63) == 0) { sred[t>>6] = s; sred[2 + (t>>6)] = q; }
        __syncthreads();
        s = sred[0] + sred[1]; q = sred[2] + sred[3];
        float mean = s * (1.f/128.f);
        float var  = q * (1.f/128.f) - mean*mean;
        float nv = (val - mean) * rsqrtf(var + EPSV) * lnh_g[t] + lnh_b[t];
        hv_ += fmaxf(nv, 0.f);
        h[blk*128 + t] = hv_;
    }
    sh[t] = hv_;
    __syncthreads();
    float au=bu_l[t], av=bv_l[t], aa=ba_l[t], ab=bb_l[t];
    for (int k = 0; k < 128; ++k) {
        float hv = sh[k];
        au = fmaf(hv, Wu_l[k*128+t], au);
        av = fmaf(hv, Wv_l[k*128+t], av);
        aa = fmaf(hv, Wa_l[k*128+t], aa);
        ab = fmaf(hv, Wb_l[k*128+t], ab);
    }
    Uh[blk*128+t]=au; Bh[blk*128+t]=ab;
    VhT[(size_t)(b*128+t)*256 + v] = av;
    AhT[(size_t)(b*128+t)*256 + v] = aa;
}

// ---------------- K4: fused layer chunk. grid = 2048; each wave owns 16 rows x 128 cols.
template<int DO_AGG>
__global__ __launch_bounds__(256) void k_layer(
    unsigned short* __restrict__ e,
    const unsigned short* __restrict__ WcT, const unsigned short* __restrict__ PWT,
    const float* __restrict__ bc_l,
    const float* __restrict__ AhT, const float* __restrict__ Bh,
    const float* __restrict__ VhT, const float* __restrict__ adj,
    const float* __restrict__ lne_g, const float* __restrict__ lne_b,
    const float* __restrict__ plo_g, const float* __restrict__ plo_b,
    const float* __restrict__ pbW_l,
    float* __restrict__ aggB)
{
    __shared__ __align__(16) char sUa[4][4096];  // per-wave private bf16 [16][128] swizzled
    __shared__ float sRedA[512];

    const int t = threadIdx.x;
    const int bi = blockIdx.x >> 2, chunk = blockIdx.x & 3;
    const int b = bi >> 8, i = bi & 255;
    const int w = t >> 6, lane = t & 63;
    const int lane16 = lane & 15, g = lane >> 4;
    const size_t rowbase = (size_t)bi * 32768;
    const int j0 = chunk*64 + w*16;
    char* sE = sUa[w];

    // --- GEMM1 A-frags: direct bf16 global -> regs (row j0+lane16, k-slice g*8 per kst)
    short8v a8[4];
    {
        const unsigned short* arow = e + rowbase + (size_t)(j0 + lane16)*128 + g*8;
        #pragma unroll
        for (int kst = 0; kst < 4; ++kst)
            a8[kst] = *(const short8v*)&arow[kst*32];
    }

    // --- GEMM1: e @ Wc + epilogue (D[j][n]: row=j0+g*4+r, col=nt*16+lane16)
    f32x4 tv[8];
    float agg[8];
    float s1[4] = {0,0,0,0}, q1[4] = {0,0,0,0};
    const int jb = j0 + g*4;
    float4 mk;
    if (DO_AGG) mk = *(const float4*)&adj[(size_t)b*393216 + (size_t)i*256 + jb];
    const float* mkp = (const float*)&mk;
    #pragma unroll
    for (int nt = 0; nt < 8; ++nt) {
        const int col = nt*16 + lane16;
        f32x4 acc = {0.f,0.f,0.f,0.f};
        #pragma unroll
        for (int kst = 0; kst < 4; ++kst) {
            short8v bfr = *(const short8v*)&WcT[col*128 + kst*32 + g*8];
            acc = __builtin_amdgcn_mfma_f32_16x16x32_bf16(a8[kst], bfr, acc, 0, 0, 0);
        }
        const float bcB = bc_l[col] + Bh[bi*128 + col];
        const float4 ah = *(const float4*)&AhT[(size_t)(b*128+col)*256 + jb];
        const float* ahp = (const float*)&ah;
        if (DO_AGG) {
            const float4 vh = *(const float4*)&VhT[(size_t)(b*128+col)*256 + jb];
            const float* vhp = (const float*)&vh;
            float a = 0.f;
            #pragma unroll
            for (int r = 0; r < 4; ++r) {
                float tvl = acc[r] + bcB + ahp[r];
                a = fmaf(mkp[r]*sigmoidf_(tvl), vhp[r], a);
                s1[r] += tvl; q1[r] = fmaf(tvl, tvl, q1[r]);
                tv[nt][r] = tvl;
            }
            agg[nt] = a;
        } else {
            #pragma unroll
            for (int r = 0; r < 4; ++r) {
                float tvl = acc[r] + bcB + ahp[r];
                s1[r] += tvl; q1[r] = fmaf(tvl, tvl, q1[r]);
                tv[nt][r] = tvl;
            }
        }
    }
    // --- row stats 1 (wave-internal 16-lane reduce)
    float mu1[4], rs1[4];
    #pragma unroll
    for (int r = 0; r < 4; ++r) {
        float s = s1[r], q = q1[r];
        s += __shfl_xor(s,1); q += __shfl_xor(q,1);
        s += __shfl_xor(s,2); q += __shfl_xor(q,2);
        s += __shfl_xor(s,4); q += __shfl_xor(q,4);
        s += __shfl_xor(s,8); q += __shfl_xor(q,8);
        float mu = s*(1.f/128.f);
        mu1[r] = mu; rs1[r] = rsqrtf(q*(1.f/128.f) - mu*mu + EPSV);
    }
    // --- LN1 + relu, stats 2
    float s2[4] = {0,0,0,0}, q2[4] = {0,0,0,0};
    #pragma unroll
    for (int nt = 0; nt < 8; ++nt) {
        const int col = nt*16 + lane16;
        const float lg = lne_g[col], lb = lne_b[col];
        #pragma unroll
        for (int r = 0; r < 4; ++r) {
            float tp = fmaxf(fmaf((tv[nt][r]-mu1[r])*rs1[r], lg, lb), 0.f);
            tv[nt][r] = tp;
            s2[r] += tp; q2[r] = fmaf(tp, tp, q2[r]);
        }
    }
    float mu2[4], rs2[4];
    #pragma unroll
    for (int r = 0; r < 4; ++r) {
        float s = s2[r], q = q2[r];
        s += __shfl_xor(s,1); q += __shfl_xor(q,1);
        s += __shfl_xor(s,2); q += __shfl_xor(q,2);
        s += __shfl_xor(s,4); q += __shfl_xor(q,4);
        s += __shfl_xor(s,8); q += __shfl_xor(q,8);
        float mu = s*(1.f/128.f);
        mu2[r] = mu; rs2[r] = rsqrtf(q*(1.f/128.f) - mu*mu + EPSV);
    }
    // --- LN2 + silu -> Ua bf16 into wave-private LDS (transpose for GEMM2 B)
    #pragma unroll
    for (int nt = 0; nt < 8; ++nt) {
        const int col = nt*16 + lane16;
        const float pg = plo_g[col], pb = plo_b[col];
        #pragma unroll
        for (int r = 0; r < 4; ++r) {
            float u = fmaf((tv[nt][r]-mu2[r])*rs2[r], pg, pb);
            u = u * sigmoidf_(u);
            const int row = g*4 + r;
            *(short*)(sE + row*256 + SWZ(row, col*2)) = (short)f2bf(u);
        }
    }
    // --- GEMM2 (swapped): D'[n][j] = plo_W^T @ u^T. B-frag = u rows (same layout as GEMM1 A).
    short8v b8[4];
    #pragma unroll
    for (int kst = 0; kst < 4; ++kst)
        b8[kst] = *(const short8v*)(sE + lane16*256 + SWZ(lane16, kst*64 + g*16));
    const int jg = j0 + lane16;   // this lane's output row
    #pragma unroll
    for (int nt = 0; nt < 8; ++nt) {
        f32x4 acc = {0.f,0.f,0.f,0.f};
        #pragma unroll
        for (int kst = 0; kst < 4; ++kst) {
            short8v aw = *(const short8v*)&PWT[(nt*16 + lane16)*128 + kst*32 + g*8];
            acc = __builtin_amdgcn_mfma_f32_16x16x32_bf16(aw, b8[kst], acc, 0, 0, 0);
        }
        const int n0 = nt*16 + g*4;
        const float4 pw4 = *(const float4*)&pbW_l[n0];
        const float* pwp = (const float*)&pw4;
        unsigned short* ep = &e[rowbase + (size_t)jg*128 + n0];
        const ushort4 ev = *(const ushort4*)ep;
        ushort4 ov;
        ov.x = f2bf(acc[0] + pwp[0] + bf2f(ev.x));
        ov.y = f2bf(acc[1] + pwp[1] + bf2f(ev.y));
        ov.z = f2bf(acc[2] + pwp[2] + bf2f(ev.z));
        ov.w = f2bf(acc[3] + pwp[3] + bf2f(ev.w));
        *(ushort4*)ep = ov;
    }

    // ---- block tail: agg reduce + atomic
    if (DO_AGG) {
        #pragma unroll
        for (int nt = 0; nt < 8; ++nt) {
            float a = agg[nt];
            a += __shfl_xor(a, 16); a += __shfl_xor(a, 32);
            if (lane < 16) sRedA[w*128 + nt*16 + lane] = a;
        }
        __syncthreads();
        if (t < 128) {
            float S = sRedA[t] + sRedA[128+t] + sRedA[256+t] + sRedA[384+t];
            atomicAdd(&aggB[bi*128 + t], S);
        }
    }
}

// ---------------- K6: GroupNorm channel partial sums (bf16 e, vectorized)
__global__ __launch_bounds__(256) void k_gstats(
    const unsigned short* __restrict__ e, float* __restrict__ gsum, float* __restrict__ gsq)
{
    __shared__ float sS[2048], sQ[2048];   // [16][128]
    const int blk = blockIdx.x, t = threadIdx.x;
    const int b = blk >> 8;
    const unsigned short* erow = e + (size_t)blk*32768;
    const int ch8 = (t & 15)*8, jgrp = t >> 4;
    float s[8], q[8];
    #pragma unroll
    for (int c = 0; c < 8; ++c) { s[c] = 0.f; q[c] = 0.f; }
    for (int it = 0; it < 16; ++it) {
        const int j = jgrp*16 + it;
        short8v v = *(const short8v*)&erow[(size_t)j*128 + ch8];
        #pragma unroll
        for (int c = 0; c < 8; ++c) {
            float f = bf2f((unsigned short)v[c]);
            s[c] += f; q[c] = fmaf(f, f, q[c]);
        }
    }
    #pragma unroll
    for (int c = 0; c < 8; ++c) { sS[jgrp*128 + ch8 + c] = s[c]; sQ[jgrp*128 + ch8 + c] = q[c]; }
    __syncthreads();
    if (t < 128) {
        float S = 0.f, Q = 0.f;
        #pragma unroll
        for (int r = 0; r < 16; ++r) { S += sS[r*128 + t]; Q += sQ[r*128 + t]; }
        atomicAdd(&gsum[b*128 + t], S);
        atomicAdd(&gsq[b*128 + t], Q);
    }
}

// ---------------- K7: finalize group stats
__global__ void k_gfin(const float* __restrict__ gsum, const float* __restrict__ gsq,
                       float* __restrict__ gmu, float* __restrict__ grs)
{
    int t = threadIdx.x; // 64
    int b = t >> 5, g = t & 31;
    int base = b*128 + g*4;
    float s = gsum[base]+gsum[base+1]+gsum[base+2]+gsum[base+3];
    float q = gsq[base]+gsq[base+1]+gsq[base+2]+gsq[base+3];
    const float invN = 1.f/(4.f*65536.f);
    float mu = s*invN;
    float var = q*invN - mu*mu;
    gmu[t] = mu;
    grs[t] = rsqrtf(var + EPSV);
}

// ---------------- K8: head: GN transform -> relu -> 1x1 conv (dot over 128 ch), bf16 e
__global__ __launch_bounds__(256) void k_head(
    const unsigned short* __restrict__ e, const float* __restrict__ gmu,
    const float* __restrict__ grs, const float* __restrict__ gn_g,
    const float* __restrict__ gn_b, const float* __restrict__ W_out,
    const float* __restrict__ b_out, float* __restrict__ out)
{
    const int blk = blockIdx.x, t = threadIdx.x;
    const int b = blk >> 8;
    const int ch8 = (t & 15)*8, jgrp = t >> 4;
    float gg[8], gb[8], wo[8];
    #pragma unroll
    for (int c = 0; c < 8; ++c) {
        const int ch = ch8 + c;
        const float mu = gmu[b*32 + (ch>>2)], rs = grs[b*32 + (ch>>2)];
        gg[c] = gn_g[ch]*rs;
        gb[c] = gn_b[ch] - mu*gg[c];
        wo[c] = W_out[ch];
    }
    const float bo = b_out[0];
    const unsigned short* erow = e + (size_t)blk*32768;
    float* orow = out + (size_t)blk*256;
    for (int it = 0; it < 16; ++it) {
        const int j = jgrp*16 + it;
        short8v v = *(const short8v*)&erow[(size_t)j*128 + ch8];
        float p = 0.f;
        #pragma unroll
        for (int c = 0; c < 8; ++c) {
            float f = bf2f((unsigned short)v[c]);
            p = fmaf(fmaxf(fmaf(f, gg[c], gb[c]), 0.f), wo[c], p);
        }
        p += __shfl_xor(p, 1); p += __shfl_xor(p, 2);
        p += __shfl_xor(p, 4); p += __shfl_xor(p, 8);
        if ((t & 15) == 0) orow[j] = p + bo;
    }
}

extern "C" void kernel_launch(void* const* d_in, const int* in_sizes, int n_in,
                              void* d_out, int out_size, void* d_ws, size_t ws_size,
                              hipStream_t stream)
{
    const int*   x      = (const int*)  d_in[0];
    const float* adj    = (const float*)d_in[1];
    const float* emb    = (const float*)d_in[2];
    const float* W_node = (const float*)d_in[3];
    const float* b_node = (const float*)d_in[4];
    const float* W_ea   = (const float*)d_in[5];
    const float* b_ea   = (const float*)d_in[6];
    const float* W_ee   = (const float*)d_in[7];
    const float* b_ee   = (const float*)d_in[8];
    const float* Wu     = (const float*)d_in[9];
    const float* bu     = (const float*)d_in[10];
    const float* Wv     = (const float*)d_in[11];
    const float* bv     = (const float*)d_in[12];
    const float* Wa     = (const float*)d_in[13];
    const float* ba     = (const float*)d_in[14];
    const float* Wb     = (const float*)d_in[15];
    const float* bb     = (const float*)d_in[16];
    const float* Wc     = (const float*)d_in[17];
    const float* bc     = (const float*)d_in[18];
    const float* lnh_g  = (const float*)d_in[19];
    const float* lnh_b  = (const float*)d_in[20];
    const float* lne_g  = (const float*)d_in[21];
    const float* lne_b  = (const float*)d_in[22];
    const float* plo_g  = (const float*)d_in[23];
    const float* plo_b  = (const float*)d_in[24];
    const float* plo_W  = (const float*)d_in[25];
    const float* plo_bW = (const float*)d_in[26];
    const float* gn_g   = (const float*)d_in[27];
    const float* gn_b   = (const float*)d_in[28];
    const float* W_out  = (const float*)d_in[29];
    const float* b_out  = (const float*)d_in[30];
    float* out = (float*)d_out;

    float* ws = (float*)d_ws;
    size_t off = 0;
    unsigned short* e = (unsigned short*)(ws + off); off += 8388608;  // 16.7M bf16 = 33.5 MB
    float* h    = ws + off; off += 65536;
    float* Uh   = ws + off; off += 65536;
    float* Bh   = ws + off; off += 65536;
    float* VhT  = ws + off; off += 65536;
    float* AhT  = ws + off; off += 65536;
    float* aggB = ws + off; off += 65536;
    float* Wcb  = ws + off; off += 768;
    float* bcb  = ws + off; off += 128;
    float* gsum = ws + off; off += 256;
    float* gsq  = ws + off; off += 256;   // contiguous with gsum
    float* gmu  = ws + off; off += 64;
    float* grs  = ws + off; off += 64;
    unsigned short* WT = (unsigned short*)(ws + off); off += 49152;  // 6 x 128x128 bf16

    k_prep<<<519, 256, 0, stream>>>(x, emb, W_node, b_node, h, aggB,
                                    W_ea, b_ea, W_ee, b_ee, Wcb, bcb,
                                    Wc, plo_W, WT);
    k_einit<<<512, 256, 0, stream>>>(adj, Wcb, bcb, e);
    hipMemsetAsync(gsum, 0, 512*sizeof(float), stream);

    for (int l = 0; l < 3; ++l) {
        k_hgemm<<<512, 128, 0, stream>>>(h, Uh, aggB,
            Wu + (size_t)l*16384, bu + l*128,
            Wv + (size_t)l*16384, bv + l*128,
            Wa + (size_t)l*16384, ba + l*128,
            Wb + (size_t)l*16384, bb + l*128,
            VhT, AhT, Bh,
            lnh_g + (l==0?0:(l-1)*128), lnh_b + (l==0?0:(l-1)*128), l > 0 ? 1 : 0);
        if (l < 2) {
            k_layer<1><<<2048, 256, 0, stream>>>(e,
                WT + (size_t)(2*l)*16384, WT + (size_t)(2*l+1)*16384,
                bc + l*128, AhT, Bh, VhT, adj,
                lne_g + l*128, lne_b + l*128,
                plo_g + l*128, plo_b + l*128,
                plo_bW + l*128, aggB);
        } else {
            k_layer<0><<<2048, 256, 0, stream>>>(e,
                WT + (size_t)(2*l)*16384, WT + (size_t)(2*l+1)*16384,
                bc + l*128, AhT, Bh, VhT, adj,
                lne_g + l*128, lne_b + l*128,
                plo_g + l*128, plo_b + l*128,
                plo_bW + l*128, aggB);
        }
    }

    k_gstats<<<512, 256, 0, stream>>>(e, gsum, gsq);
    k_gfin<<<1, 64, 0, stream>>>(gsum, gsq, gmu, grs);
    k_head<<<512, 256, 0, stream>>>(e, gmu, grs, gn_g, gn_b, W_out, b_out, out);
}

// Round 6
// 232.113 us; speedup vs baseline: 4.5878x; 1.5777x over previous
//
#include <hip/hip_runtime.h>
#include <cstdint>
#include <cstddef>

// GNNDi: B=2, V=256, H=128, L=3, GroupNorm32 head. e stored [b][i][j][h] bf16.

#define EPSV 1e-5f

typedef __attribute__((ext_vector_type(8))) short short8v;  // 8 bf16
typedef __attribute__((ext_vector_type(4))) float f32x4;

__device__ __forceinline__ float sigmoidf_(float x) { return 1.f / (1.f + __expf(-x)); }

__device__ __forceinline__ unsigned short f2bf(float x) {
    unsigned int u = __float_as_uint(x);
    unsigned int r = u + 0x7FFFu + ((u >> 16) & 1u);   // RNE
    return (unsigned short)(r >> 16);
}
__device__ __forceinline__ float bf2f(unsigned short u) {
    return __uint_as_float(((unsigned int)u) << 16);
}
#define SWZ(row, cb) ((cb) ^ (((row) & 7) << 4))

// ---------------- K_prep: node embed + aggB zero (blocks 0..511), wcomb (512), weight transpose (513..518)
__global__ void k_prep(const int* __restrict__ x, const float* __restrict__ emb,
                       const float* __restrict__ W_node, const float* __restrict__ b_node,
                       float* __restrict__ h, float* __restrict__ aggB,
                       const float* __restrict__ W_ea, const float* __restrict__ b_ea,
                       const float* __restrict__ W_ee, const float* __restrict__ b_ee,
                       float* __restrict__ Wcb, float* __restrict__ bcb,
                       const float* __restrict__ Wc, const float* __restrict__ PW,
                       unsigned short* __restrict__ WT)
{
    const int blk = blockIdx.x, t = threadIdx.x;
    if (blk < 512) {
        __shared__ float se[128];
        if (t < 128) { se[t] = emb[x[blk]*128 + t]; aggB[blk*128 + t] = 0.f; }
        __syncthreads();
        if (t < 128) {
            float acc = b_node[t];
            for (int k = 0; k < 128; ++k) acc = fmaf(se[k], W_node[k*128+t], acc);
            h[blk*128+t] = acc;
        }
    } else if (blk == 512) {
        if (t < 128) {
            float wc0=0,wc1=0,wc2=0,wc3=0,wc4=0,wc5=0,bv=0;
            for (int m = 0; m < 128; ++m) {
                float we = W_ee[m*128 + t];
                wc0 = fmaf(W_ea[0*128+m], we, wc0);
                wc1 = fmaf(W_ea[1*128+m], we, wc1);
                wc2 = fmaf(W_ea[2*128+m], we, wc2);
                wc3 = fmaf(W_ea[3*128+m], we, wc3);
                wc4 = fmaf(W_ea[4*128+m], we, wc4);
                wc5 = fmaf(W_ea[5*128+m], we, wc5);
                bv  = fmaf(b_ea[m], we, bv);
            }
            Wcb[0*128+t]=wc0; Wcb[1*128+t]=wc1; Wcb[2*128+t]=wc2;
            Wcb[3*128+t]=wc3; Wcb[4*128+t]=wc4; Wcb[5*128+t]=wc5;
            bcb[t] = bv + b_ee[t];
        }
    } else {
        const int m = blk - 513;            // 0..5 = layer*2 + (0:Wc, 1:plo_W)
        const int l = m >> 1;
        const float* src = (m & 1) ? (PW + (size_t)l*16384) : (Wc + (size_t)l*16384);
        unsigned short* dst = WT + (size_t)m*16384;
        for (int idx = t; idx < 16384; idx += 256) {
            int n = idx >> 7, k = idx & 127;
            dst[idx] = f2bf(src[k*128 + n]);   // [n][k] bf16 (transposed)
        }
    }
}

// ---------------- K2: e0 init (bf16 out, vectorized)
__global__ __launch_bounds__(256) void k_einit(
    const float* __restrict__ adj, const float* __restrict__ Wcb,
    const float* __restrict__ bcb, unsigned short* __restrict__ e)
{
    __shared__ float sAdj[6*256];
    const int blk = blockIdx.x, t = threadIdx.x;
    const int b = blk >> 8, i = blk & 255;
    const float* arow = adj + (size_t)b*393216 + (size_t)i*256;
    for (int idx = t; idx < 1536; idx += 256)
        sAdj[idx] = arow[(idx >> 8)*65536 + (idx & 255)];
    const int ch8 = (t & 15) * 8, jgrp = t >> 4;
    float w[6][8], bb8[8];
    #pragma unroll
    for (int c = 0; c < 8; ++c) bb8[c] = bcb[ch8 + c];
    #pragma unroll
    for (int m = 0; m < 6; ++m)
        #pragma unroll
        for (int c = 0; c < 8; ++c) w[m][c] = Wcb[m*128 + ch8 + c];
    __syncthreads();
    unsigned short* erow = e + (size_t)blk*32768;
    for (int it = 0; it < 16; ++it) {
        const int j = jgrp*16 + it;
        float a[6];
        #pragma unroll
        for (int m = 0; m < 6; ++m) a[m] = sAdj[m*256 + j];
        short8v o;
        #pragma unroll
        for (int c = 0; c < 8; ++c) {
            float v = bb8[c];
            #pragma unroll
            for (int m = 0; m < 6; ++m) v = fmaf(a[m], w[m][c], v);
            o[c] = (short)f2bf(v);
        }
        *(short8v*)&erow[(size_t)j*128 + ch8] = o;
    }
}

// ---------------- K3: fused h-update (from prev layer) + 4 h-GEMMs; zeroes aggB
__global__ void k_hgemm(float* __restrict__ h, float* __restrict__ Uh, float* __restrict__ aggB,
    const float* __restrict__ Wu_l, const float* __restrict__ bu_l,
    const float* __restrict__ Wv_l, const float* __restrict__ bv_l,
    const float* __restrict__ Wa_l, const float* __restrict__ ba_l,
    const float* __restrict__ Wb_l, const float* __restrict__ bb_l,
    float* __restrict__ VhT, float* __restrict__ AhT, float* __restrict__ Bh,
    const float* __restrict__ lnh_g, const float* __restrict__ lnh_b, int upd)
{
    __shared__ float sh[128];
    __shared__ float sred[4];
    int blk = blockIdx.x, t = threadIdx.x;
    int b = blk >> 8, v = blk & 255;
    float hv_ = h[blk*128 + t];
    if (upd) {
        float val = Uh[blk*128 + t] + aggB[blk*128 + t];
        aggB[blk*128 + t] = 0.f;
        float s = val, q = val*val;
        #pragma unroll
        for (int off = 32; off; off >>= 1) { s += __shfl_down(s, off); q += __shfl_down(q, off); }
        if ((t & 63) == 0) { sred[t>>6] = s; sred[2 + (t>>6)] = q; }
        __syncthreads();
        s = sred[0] + sred[1]; q = sred[2] + sred[3];
        float mean = s * (1.f/128.f);
        float var  = q * (1.f/128.f) - mean*mean;
        float nv = (val - mean) * rsqrtf(var + EPSV) * lnh_g[t] + lnh_b[t];
        hv_ += fmaxf(nv, 0.f);
        h[blk*128 + t] = hv_;
    }
    sh[t] = hv_;
    __syncthreads();
    float au=bu_l[t], av=bv_l[t], aa=ba_l[t], ab=bb_l[t];
    for (int k = 0; k < 128; ++k) {
        float hv = sh[k];
        au = fmaf(hv, Wu_l[k*128+t], au);
        av = fmaf(hv, Wv_l[k*128+t], av);
        aa = fmaf(hv, Wa_l[k*128+t], aa);
        ab = fmaf(hv, Wb_l[k*128+t], ab);
    }
    Uh[blk*128+t]=au; Bh[blk*128+t]=ab;
    VhT[(size_t)(b*128+t)*256 + v] = av;
    AhT[(size_t)(b*128+t)*256 + v] = aa;
}

// ---------------- K4: fused layer chunk. grid = 2048; each wave owns 16 rows x 128 cols.
// Weights staged in swizzled LDS (Wc then PWT) to kill line-scattered L1 gathers.
template<int DO_AGG>
__global__ __launch_bounds__(256) void k_layer(
    unsigned short* __restrict__ e,
    const unsigned short* __restrict__ WcT, const unsigned short* __restrict__ PWT,
    const float* __restrict__ bc_l,
    const float* __restrict__ AhT, const float* __restrict__ Bh,
    const float* __restrict__ VhT, const float* __restrict__ adj,
    const float* __restrict__ lne_g, const float* __restrict__ lne_b,
    const float* __restrict__ plo_g, const float* __restrict__ plo_b,
    const float* __restrict__ pbW_l,
    float* __restrict__ aggB)
{
    __shared__ __align__(16) char sW[32768];     // weight matrix bf16 [128 rows][256B], swizzled
    __shared__ __align__(16) char sUa[4][4096];  // per-wave private bf16 [16][128] swizzled
    __shared__ float sRedA[512];

    const int t = threadIdx.x;
    const int bi = blockIdx.x >> 2, chunk = blockIdx.x & 3;
    const int b = bi >> 8, i = bi & 255;
    const int w = t >> 6, lane = t & 63;
    const int lane16 = lane & 15, g = lane >> 4;
    const size_t rowbase = (size_t)bi * 32768;
    const int j0 = chunk*64 + w*16;
    char* sE = sUa[w];

    // --- GEMM1 A-frags: direct bf16 global -> regs (issue early)
    short8v a8[4];
    {
        const unsigned short* arow = e + rowbase + (size_t)(j0 + lane16)*128 + g*8;
        #pragma unroll
        for (int kst = 0; kst < 4; ++kst)
            a8[kst] = *(const short8v*)&arow[kst*32];
    }

    // --- stage Wc into LDS (dense global reads, swizzled LDS writes)
    #pragma unroll
    for (int p = 0; p < 8; ++p) {
        const int idx = t*8 + p*2048;            // short index
        const int n = idx >> 7, cb = (idx & 127) << 1;
        *(short8v*)(sW + n*256 + SWZ(n, cb)) = *(const short8v*)&WcT[idx];
    }
    __syncthreads();

    // --- GEMM1: e @ Wc + epilogue (D[j][n]: row=j0+g*4+r, col=nt*16+lane16)
    f32x4 tv[8];
    float agg[8];
    float s1[4] = {0,0,0,0}, q1[4] = {0,0,0,0};
    const int jb = j0 + g*4;
    float4 mk;
    if (DO_AGG) mk = *(const float4*)&adj[(size_t)b*393216 + (size_t)i*256 + jb];
    const float* mkp = (const float*)&mk;
    #pragma unroll
    for (int nt = 0; nt < 8; ++nt) {
        const int col = nt*16 + lane16;
        f32x4 acc = {0.f,0.f,0.f,0.f};
        #pragma unroll
        for (int kst = 0; kst < 4; ++kst) {
            short8v bfr = *(const short8v*)(sW + col*256 + SWZ(col, kst*64 + g*16));
            acc = __builtin_amdgcn_mfma_f32_16x16x32_bf16(a8[kst], bfr, acc, 0, 0, 0);
        }
        const float bcB = bc_l[col] + Bh[bi*128 + col];
        const float4 ah = *(const float4*)&AhT[(size_t)(b*128+col)*256 + jb];
        const float* ahp = (const float*)&ah;
        if (DO_AGG) {
            const float4 vh = *(const float4*)&VhT[(size_t)(b*128+col)*256 + jb];
            const float* vhp = (const float*)&vh;
            float a = 0.f;
            #pragma unroll
            for (int r = 0; r < 4; ++r) {
                float tvl = acc[r] + bcB + ahp[r];
                a = fmaf(mkp[r]*sigmoidf_(tvl), vhp[r], a);
                s1[r] += tvl; q1[r] = fmaf(tvl, tvl, q1[r]);
                tv[nt][r] = tvl;
            }
            agg[nt] = a;
        } else {
            #pragma unroll
            for (int r = 0; r < 4; ++r) {
                float tvl = acc[r] + bcB + ahp[r];
                s1[r] += tvl; q1[r] = fmaf(tvl, tvl, q1[r]);
                tv[nt][r] = tvl;
            }
        }
    }
    // --- row stats 1 (wave-internal 16-lane reduce)
    float mu1[4], rs1[4];
    #pragma unroll
    for (int r = 0; r < 4; ++r) {
        float s = s1[r], q = q1[r];
        s += __shfl_xor(s,1); q += __shfl_xor(q,1);
        s += __shfl_xor(s,2); q += __shfl_xor(q,2);
        s += __shfl_xor(s,4); q += __shfl_xor(q,4);
        s += __shfl_xor(s,8); q += __shfl_xor(q,8);
        float mu = s*(1.f/128.f);
        mu1[r] = mu; rs1[r] = rsqrtf(q*(1.f/128.f) - mu*mu + EPSV);
    }
    // --- LN1 + relu, stats 2
    float s2[4] = {0,0,0,0}, q2[4] = {0,0,0,0};
    #pragma unroll
    for (int nt = 0; nt < 8; ++nt) {
        const int col = nt*16 + lane16;
        const float lg = lne_g[col], lb = lne_b[col];
        #pragma unroll
        for (int r = 0; r < 4; ++r) {
            float tp = fmaxf(fmaf((tv[nt][r]-mu1[r])*rs1[r], lg, lb), 0.f);
            tv[nt][r] = tp;
            s2[r] += tp; q2[r] = fmaf(tp, tp, q2[r]);
        }
    }
    float mu2[4], rs2[4];
    #pragma unroll
    for (int r = 0; r < 4; ++r) {
        float s = s2[r], q = q2[r];
        s += __shfl_xor(s,1); q += __shfl_xor(q,1);
        s += __shfl_xor(s,2); q += __shfl_xor(q,2);
        s += __shfl_xor(s,4); q += __shfl_xor(q,4);
        s += __shfl_xor(s,8); q += __shfl_xor(q,8);
        float mu = s*(1.f/128.f);
        mu2[r] = mu; rs2[r] = rsqrtf(q*(1.f/128.f) - mu*mu + EPSV);
    }
    // --- LN2 + silu -> Ua bf16 into wave-private LDS (transpose for GEMM2 B)
    #pragma unroll
    for (int nt = 0; nt < 8; ++nt) {
        const int col = nt*16 + lane16;
        const float pg = plo_g[col], pb = plo_b[col];
        #pragma unroll
        for (int r = 0; r < 4; ++r) {
            float u = fmaf((tv[nt][r]-mu2[r])*rs2[r], pg, pb);
            u = u * sigmoidf_(u);
            const int row = g*4 + r;
            *(short*)(sE + row*256 + SWZ(row, col*2)) = (short)f2bf(u);
        }
    }
    // --- B-frags for GEMM2 from own wave's Ua slice (same-wave DS ordering)
    short8v b8[4];
    #pragma unroll
    for (int kst = 0; kst < 4; ++kst)
        b8[kst] = *(const short8v*)(sE + lane16*256 + SWZ(lane16, kst*64 + g*16));

    __syncthreads();   // everyone done reading Wc
    // --- stage PWT into LDS
    #pragma unroll
    for (int p = 0; p < 8; ++p) {
        const int idx = t*8 + p*2048;
        const int n = idx >> 7, cb = (idx & 127) << 1;
        *(short8v*)(sW + n*256 + SWZ(n, cb)) = *(const short8v*)&PWT[idx];
    }
    __syncthreads();

    // --- GEMM2 (swapped): D'[n][j] = plo_W^T @ u^T. A-frag = PWT rows from LDS.
    const int jg = j0 + lane16;   // this lane's output row
    #pragma unroll
    for (int nt = 0; nt < 8; ++nt) {
        const int an = nt*16 + lane16;
        f32x4 acc = {0.f,0.f,0.f,0.f};
        #pragma unroll
        for (int kst = 0; kst < 4; ++kst) {
            short8v aw = *(const short8v*)(sW + an*256 + SWZ(an, kst*64 + g*16));
            acc = __builtin_amdgcn_mfma_f32_16x16x32_bf16(aw, b8[kst], acc, 0, 0, 0);
        }
        const int n0 = nt*16 + g*4;
        const float4 pw4 = *(const float4*)&pbW_l[n0];
        const float* pwp = (const float*)&pw4;
        unsigned short* ep = &e[rowbase + (size_t)jg*128 + n0];
        const ushort4 ev = *(const ushort4*)ep;
        ushort4 ov;
        ov.x = f2bf(acc[0] + pwp[0] + bf2f(ev.x));
        ov.y = f2bf(acc[1] + pwp[1] + bf2f(ev.y));
        ov.z = f2bf(acc[2] + pwp[2] + bf2f(ev.z));
        ov.w = f2bf(acc[3] + pwp[3] + bf2f(ev.w));
        *(ushort4*)ep = ov;
    }

    // ---- block tail: agg reduce + atomic
    if (DO_AGG) {
        #pragma unroll
        for (int nt = 0; nt < 8; ++nt) {
            float a = agg[nt];
            a += __shfl_xor(a, 16); a += __shfl_xor(a, 32);
            if (lane < 16) sRedA[w*128 + nt*16 + lane] = a;
        }
        __syncthreads();
        if (t < 128) {
            float S = sRedA[t] + sRedA[128+t] + sRedA[256+t] + sRedA[384+t];
            atomicAdd(&aggB[bi*128 + t], S);
        }
    }
}

// ---------------- K6: GroupNorm channel partial sums (bf16 e, vectorized)
__global__ __launch_bounds__(256) void k_gstats(
    const unsigned short* __restrict__ e, float* __restrict__ gsum, float* __restrict__ gsq)
{
    __shared__ float sS[2048], sQ[2048];   // [16][128]
    const int blk = blockIdx.x, t = threadIdx.x;
    const int b = blk >> 8;
    const unsigned short* erow = e + (size_t)blk*32768;
    const int ch8 = (t & 15)*8, jgrp = t >> 4;
    float s[8], q[8];
    #pragma unroll
    for (int c = 0; c < 8; ++c) { s[c] = 0.f; q[c] = 0.f; }
    for (int it = 0; it < 16; ++it) {
        const int j = jgrp*16 + it;
        short8v v = *(const short8v*)&erow[(size_t)j*128 + ch8];
        #pragma unroll
        for (int c = 0; c < 8; ++c) {
            float f = bf2f((unsigned short)v[c]);
            s[c] += f; q[c] = fmaf(f, f, q[c]);
        }
    }
    #pragma unroll
    for (int c = 0; c < 8; ++c) { sS[jgrp*128 + ch8 + c] = s[c]; sQ[jgrp*128 + ch8 + c] = q[c]; }
    __syncthreads();
    if (t < 128) {
        float S = 0.f, Q = 0.f;
        #pragma unroll
        for (int r = 0; r < 16; ++r) { S += sS[r*128 + t]; Q += sQ[r*128 + t]; }
        atomicAdd(&gsum[b*128 + t], S);
        atomicAdd(&gsq[b*128 + t], Q);
    }
}

// ---------------- K7: finalize group stats
__global__ void k_gfin(const float* __restrict__ gsum, const float* __restrict__ gsq,
                       float* __restrict__ gmu, float* __restrict__ grs)
{
    int t = threadIdx.x; // 64
    int b = t >> 5, g = t & 31;
    int base = b*128 + g*4;
    float s = gsum[base]+gsum[base+1]+gsum[base+2]+gsum[base+3];
    float q = gsq[base]+gsq[base+1]+gsq[base+2]+gsq[base+3];
    const float invN = 1.f/(4.f*65536.f);
    float mu = s*invN;
    float var = q*invN - mu*mu;
    gmu[t] = mu;
    grs[t] = rsqrtf(var + EPSV);
}

// ---------------- K8: head: GN transform -> relu -> 1x1 conv (dot over 128 ch), bf16 e
__global__ __launch_bounds__(256) void k_head(
    const unsigned short* __restrict__ e, const float* __restrict__ gmu,
    const float* __restrict__ grs, const float* __restrict__ gn_g,
    const float* __restrict__ gn_b, const float* __restrict__ W_out,
    const float* __restrict__ b_out, float* __restrict__ out)
{
    const int blk = blockIdx.x, t = threadIdx.x;
    const int b = blk >> 8;
    const int ch8 = (t & 15)*8, jgrp = t >> 4;
    float gg[8], gb[8], wo[8];
    #pragma unroll
    for (int c = 0; c < 8; ++c) {
        const int ch = ch8 + c;
        const float mu = gmu[b*32 + (ch>>2)], rs = grs[b*32 + (ch>>2)];
        gg[c] = gn_g[ch]*rs;
        gb[c] = gn_b[ch] - mu*gg[c];
        wo[c] = W_out[ch];
    }
    const float bo = b_out[0];
    const unsigned short* erow = e + (size_t)blk*32768;
    float* orow = out + (size_t)blk*256;
    for (int it = 0; it < 16; ++it) {
        const int j = jgrp*16 + it;
        short8v v = *(const short8v*)&erow[(size_t)j*128 + ch8];
        float p = 0.f;
        #pragma unroll
        for (int c = 0; c < 8; ++c) {
            float f = bf2f((unsigned short)v[c]);
            p = fmaf(fmaxf(fmaf(f, gg[c], gb[c]), 0.f), wo[c], p);
        }
        p += __shfl_xor(p, 1); p += __shfl_xor(p, 2);
        p += __shfl_xor(p, 4); p += __shfl_xor(p, 8);
        if ((t & 15) == 0) orow[j] = p + bo;
    }
}

extern "C" void kernel_launch(void* const* d_in, const int* in_sizes, int n_in,
                              void* d_out, int out_size, void* d_ws, size_t ws_size,
                              hipStream_t stream)
{
    const int*   x      = (const int*)  d_in[0];
    const float* adj    = (const float*)d_in[1];
    const float* emb    = (const float*)d_in[2];
    const float* W_node = (const float*)d_in[3];
    const float* b_node = (const float*)d_in[4];
    const float* W_ea   = (const float*)d_in[5];
    const float* b_ea   = (const float*)d_in[6];
    const float* W_ee   = (const float*)d_in[7];
    const float* b_ee   = (const float*)d_in[8];
    const float* Wu     = (const float*)d_in[9];
    const float* bu     = (const float*)d_in[10];
    const float* Wv     = (const float*)d_in[11];
    const float* bv     = (const float*)d_in[12];
    const float* Wa     = (const float*)d_in[13];
    const float* ba     = (const float*)d_in[14];
    const float* Wb     = (const float*)d_in[15];
    const float* bb     = (const float*)d_in[16];
    const float* Wc     = (const float*)d_in[17];
    const float* bc     = (const float*)d_in[18];
    const float* lnh_g  = (const float*)d_in[19];
    const float* lnh_b  = (const float*)d_in[20];
    const float* lne_g  = (const float*)d_in[21];
    const float* lne_b  = (const float*)d_in[22];
    const float* plo_g  = (const float*)d_in[23];
    const float* plo_b  = (const float*)d_in[24];
    const float* plo_W  = (const float*)d_in[25];
    const float* plo_bW = (const float*)d_in[26];
    const float* gn_g   = (const float*)d_in[27];
    const float* gn_b   = (const float*)d_in[28];
    const float* W_out  = (const float*)d_in[29];
    const float* b_out  = (const float*)d_in[30];
    float* out = (float*)d_out;

    float* ws = (float*)d_ws;
    size_t off = 0;
    unsigned short* e = (unsigned short*)(ws + off); off += 8388608;  // 16.7M bf16 = 33.5 MB
    float* h    = ws + off; off += 65536;
    float* Uh   = ws + off; off += 65536;
    float* Bh   = ws + off; off += 65536;
    float* VhT  = ws + off; off += 65536;
    float* AhT  = ws + off; off += 65536;
    float* aggB = ws + off; off += 65536;
    float* Wcb  = ws + off; off += 768;
    float* bcb  = ws + off; off += 128;
    float* gsum = ws + off; off += 256;
    float* gsq  = ws + off; off += 256;   // contiguous with gsum
    float* gmu  = ws + off; off += 64;
    float* grs  = ws + off; off += 64;
    unsigned short* WT = (unsigned short*)(ws + off); off += 49152;  // 6 x 128x128 bf16

    k_prep<<<519, 256, 0, stream>>>(x, emb, W_node, b_node, h, aggB,
                                    W_ea, b_ea, W_ee, b_ee, Wcb, bcb,
                                    Wc, plo_W, WT);
    k_einit<<<512, 256, 0, stream>>>(adj, Wcb, bcb, e);
    hipMemsetAsync(gsum, 0, 512*sizeof(float), stream);

    for (int l = 0; l < 3; ++l) {
        k_hgemm<<<512, 128, 0, stream>>>(h, Uh, aggB,
            Wu + (size_t)l*16384, bu + l*128,
            Wv + (size_t)l*16384, bv + l*128,
            Wa + (size_t)l*16384, ba + l*128,
            Wb + (size_t)l*16384, bb + l*128,
            VhT, AhT, Bh,
            lnh_g + (l==0?0:(l-1)*128), lnh_b + (l==0?0:(l-1)*128), l > 0 ? 1 : 0);
        if (l < 2) {
            k_layer<1><<<2048, 256, 0, stream>>>(e,
                WT + (size_t)(2*l)*16384, WT + (size_t)(2*l+1)*16384,
                bc + l*128, AhT, Bh, VhT, adj,
                lne_g + l*128, lne_b + l*128,
                plo_g + l*128, plo_b + l*128,
                plo_bW + l*128, aggB);
        } else {
            k_layer<0><<<2048, 256, 0, stream>>>(e,
                WT + (size_t)(2*l)*16384, WT + (size_t)(2*l+1)*16384,
                bc + l*128, AhT, Bh, VhT, adj,
                lne_g + l*128, lne_b + l*128,
                plo_g + l*128, plo_b + l*128,
                plo_bW + l*128, aggB);
        }
    }

    k_gstats<<<512, 256, 0, stream>>>(e, gsum, gsq);
    k_gfin<<<1, 64, 0, stream>>>(gsum, gsq, gmu, grs);
    k_head<<<512, 256, 0, stream>>>(e, gmu, grs, gn_g, gn_b, W_out, b_out, out);
}